// Round 4
// baseline (17494.620 us; speedup 1.0000x reference)
//
#include <hip/hip_runtime.h>
#include <hip/hip_bf16.h>

#define N_NODES 100000
#define R_REL   8
#define E_EDGES 800000
#define D_FEAT  128
#define B_BASES 4
#define RE      (R_REL * E_EDGES)          // 6.4M edges

// coarse binning: bucket = dst >> 9 (512 nodes per bucket)
#define NB_BUCKETS 196                     // ceil(100000/512)
#define BKT_CAP    36864                   // mean 32653, +23 sigma slack
#define BIN_EPT    16
#define BIN_TPB    256
#define BIN_CHUNK  (BIN_EPT * BIN_TPB)     // 4096 edges per WG

// aggregation: 32 sub-WGs per bucket, 16 nodes each
#define AGG_TPB    512
#define STASH_CAP  2048                    // expected ~1020 records

__global__ __launch_bounds__(256) void init_cursor_kernel(int* __restrict__ gcursor) {
    int t = threadIdx.x;
    if (t < NB_BUCKETS) gcursor[t] = t * BKT_CAP;
}

// x -> bf16 (only used when workspace is large enough)
__global__ __launch_bounds__(256) void xcvt_kernel(
    const float* __restrict__ x, __hip_bfloat162* __restrict__ xb) {
    int i = blockIdx.x * 256 + threadIdx.x;          // over N*D/2 pairs
    if (i >= N_NODES * D_FEAT / 2) return;
    float2 v = *(const float2*)(x + 2 * (size_t)i);
    xb[i] = __float22bfloat162_rn(v);
}

// ---- pass 1: partition edges into coarse dst-buckets --------------------
// record = src(17b) | dst_low(9b)<<17 | r(3b)<<26
__global__ __launch_bounds__(256) void bin_kernel(
    const int* __restrict__ src, const int* __restrict__ dst,
    int* __restrict__ gcursor, int* __restrict__ ebuf) {
    __shared__ int hist[NB_BUCKETS];
    __shared__ int base[NB_BUCKETS];
    __shared__ int lcur[NB_BUCKETS];
    int t = threadIdx.x;
    for (int i = t; i < NB_BUCKETS; i += 256) { hist[i] = 0; lcur[i] = 0; }
    __syncthreads();

    int e0 = blockIdx.x * BIN_CHUNK;
    int rec[BIN_EPT];
    int bkt[BIN_EPT];
#pragma unroll
    for (int i = 0; i < BIN_EPT; ++i) {
        int e = e0 + i * BIN_TPB + t;                // coalesced
        if (e < RE) {
            int d = dst[e];
            int s = src[e];
            int r = e / E_EDGES;                     // magic-mul division
            bkt[i] = d >> 9;
            rec[i] = s | ((d & 511) << 17) | (r << 26);
            atomicAdd(&hist[bkt[i]], 1);
        } else bkt[i] = -1;
    }
    __syncthreads();
    for (int i = t; i < NB_BUCKETS; i += 256)
        base[i] = (hist[i] > 0) ? atomicAdd(&gcursor[i], hist[i]) : 0;
    __syncthreads();
#pragma unroll
    for (int i = 0; i < BIN_EPT; ++i) {
        if (bkt[i] >= 0) {
            int p = base[bkt[i]] + atomicAdd(&lcur[bkt[i]], 1);
            if (p < (bkt[i] + 1) * BKT_CAP) ebuf[p] = rec[i];   // never overflows (fixed input)
        }
    }
}

// ---- pass 2: per-16-node LDS aggregation -> bf16 y ----------------------
// y[n][b*128+f] = sum_r w_comp[r][b]/max(deg_{r,n},1) * sum_{e in seg(n,r)} x[src_e][f]
template <bool XBF16>
__global__ __launch_bounds__(512) void agg_kernel(
    const float* __restrict__ x,
    const __hip_bfloat16* __restrict__ xb,
    const float* __restrict__ w_comp,
    const int* __restrict__ gcursor,
    const int* __restrict__ ebuf,
    __hip_bfloat162* __restrict__ y) {
    __shared__ float accum[16 * 512];    // 32 KB: 16 nodes x 512 concat-feats
    __shared__ int   stash[STASH_CAP];   // 8 KB
    __shared__ float coef[16 * 32];      // c[n][r][b]  (2 KB)
    __shared__ int   dcnt[16 * 8];       // degree histogram
    __shared__ int   scount;

    const int bucket = blockIdx.x >> 5;
    const int sub    = blockIdx.x & 31;
    const int nlo    = sub * 16;         // node-low within bucket
    const int t      = threadIdx.x;

    for (int i = t; i < 16 * 512; i += AGG_TPB) accum[i] = 0.f;
    for (int i = t; i < 128; i += AGG_TPB) dcnt[i] = 0;
    if (t == 0) scount = 0;
    __syncthreads();

    // scan bucket records, stash the ones for my 16 nodes, histogram degrees
    int cnt = gcursor[bucket] - bucket * BKT_CAP;
    if (cnt > BKT_CAP) cnt = BKT_CAP;
    const int* brec = ebuf + bucket * BKT_CAP;
    for (int i = t; i < cnt; i += AGG_TPB) {
        int rec = brec[i];
        unsigned dn = (unsigned)(((rec >> 17) & 511) - nlo);
        if (dn < 16u) {
            int idx = atomicAdd(&scount, 1);
            if (idx < STASH_CAP) {
                stash[idx] = rec;
                atomicAdd(&dcnt[dn * 8 + (rec >> 26)], 1);
            }
        }
    }
    __syncthreads();

    // coefficients: c[n][r][b] = w_comp[r][b] / max(deg,1)
    if (t < 512) {
        int n = t >> 5, r = (t >> 2) & 7, b = t & 3;
        int d = dcnt[n * 8 + r];
        coef[t] = w_comp[r * B_BASES + b] / (float)(d > 1 ? d : 1);
    }
    __syncthreads();

    // wave-per-record accumulate; lane covers feats (lane, lane+64) -> 2-way banks (free)
    int nrec = scount < STASH_CAP ? scount : STASH_CAP;
    int wid = t >> 6, lane = t & 63;
    for (int j = wid; j < nrec; j += 8) {
        int rec = stash[j];
        int s   = rec & 0x1FFFF;
        int dn  = ((rec >> 17) & 511) - nlo;
        int r   = rec >> 26;
        float v0, v1;
        if (XBF16) {
            v0 = __bfloat162float(xb[(size_t)s * D_FEAT + lane]);
            v1 = __bfloat162float(xb[(size_t)s * D_FEAT + 64 + lane]);
        } else {
            v0 = x[(size_t)s * D_FEAT + lane];
            v1 = x[(size_t)s * D_FEAT + 64 + lane];
        }
        const float* cf = &coef[dn * 32 + r * 4];
        float* ab = &accum[dn * 512];
#pragma unroll
        for (int b = 0; b < 4; ++b) {
            float c = cf[b];
            atomicAdd(&ab[b * 128 + lane],      c * v0);
            atomicAdd(&ab[b * 128 + 64 + lane], c * v1);
        }
    }
    __syncthreads();

    // emit y: y_u32[node*256 + p] packs concat-feats (2p, 2p+1)
    int node0 = bucket * 512 + nlo;
    for (int i = t; i < 16 * 256; i += AGG_TPB) {
        int n = i >> 8, p = i & 255;
        int node = node0 + n;
        if (node < N_NODES) {
            float2 f = make_float2(accum[n * 512 + 2 * p], accum[n * 512 + 2 * p + 1]);
            y[(size_t)node * 256 + p] = __float22bfloat162_rn(f);
        }
    }
}

// ---- big GEMM: out = relu([y(bf16) | x] @ [bases ; loop_weight] + bias) ---
__global__ __launch_bounds__(256) void gemm_big_kernel(
    const uint* __restrict__ y,            // [N][256] packed bf16 pairs
    const float* __restrict__ x,
    const float* __restrict__ bases,       // [512][128] stacked
    const float* __restrict__ loopw,       // [128][128]
    const float* __restrict__ bias,
    float* __restrict__ C) {
    const int tid  = threadIdx.x;
    const int cg   = tid & 31;
    const int rg   = tid >> 5;
    const int col  = cg << 2;
    const int row0 = blockIdx.x * 64 + rg * 8;

    float4 acc[8];
#pragma unroll
    for (int i = 0; i < 8; ++i) acc[i] = make_float4(0.f, 0.f, 0.f, 0.f);

    int rowc[8];
#pragma unroll
    for (int i = 0; i < 8; ++i) {
        int m = row0 + i;
        rowc[i] = m < N_NODES ? m : N_NODES - 1;
    }

    for (int k0 = 0; k0 < 512; k0 += 4) {
        float4 w0 = *(const float4*)(bases + (k0 + 0) * D_FEAT + col);
        float4 w1 = *(const float4*)(bases + (k0 + 1) * D_FEAT + col);
        float4 w2 = *(const float4*)(bases + (k0 + 2) * D_FEAT + col);
        float4 w3 = *(const float4*)(bases + (k0 + 3) * D_FEAT + col);
#pragma unroll
        for (int i = 0; i < 8; ++i) {
            uint2 u = *(const uint2*)(y + (size_t)rowc[i] * 256 + (k0 >> 1));
            float a0 = __uint_as_float(u.x << 16);
            float a1 = __uint_as_float(u.x & 0xFFFF0000u);
            float a2 = __uint_as_float(u.y << 16);
            float a3 = __uint_as_float(u.y & 0xFFFF0000u);
            acc[i].x = fmaf(a0, w0.x, fmaf(a1, w1.x, fmaf(a2, w2.x, fmaf(a3, w3.x, acc[i].x))));
            acc[i].y = fmaf(a0, w0.y, fmaf(a1, w1.y, fmaf(a2, w2.y, fmaf(a3, w3.y, acc[i].y))));
            acc[i].z = fmaf(a0, w0.z, fmaf(a1, w1.z, fmaf(a2, w2.z, fmaf(a3, w3.z, acc[i].z))));
            acc[i].w = fmaf(a0, w0.w, fmaf(a1, w1.w, fmaf(a2, w2.w, fmaf(a3, w3.w, acc[i].w))));
        }
    }
    for (int k0 = 0; k0 < 128; k0 += 4) {
        float4 w0 = *(const float4*)(loopw + (k0 + 0) * D_FEAT + col);
        float4 w1 = *(const float4*)(loopw + (k0 + 1) * D_FEAT + col);
        float4 w2 = *(const float4*)(loopw + (k0 + 2) * D_FEAT + col);
        float4 w3 = *(const float4*)(loopw + (k0 + 3) * D_FEAT + col);
#pragma unroll
        for (int i = 0; i < 8; ++i) {
            float4 a = *(const float4*)(x + (size_t)rowc[i] * D_FEAT + k0);
            acc[i].x = fmaf(a.x, w0.x, fmaf(a.y, w1.x, fmaf(a.z, w2.x, fmaf(a.w, w3.x, acc[i].x))));
            acc[i].y = fmaf(a.x, w0.y, fmaf(a.y, w1.y, fmaf(a.z, w2.y, fmaf(a.w, w3.y, acc[i].y))));
            acc[i].z = fmaf(a.x, w0.z, fmaf(a.y, w1.z, fmaf(a.z, w2.z, fmaf(a.w, w3.z, acc[i].z))));
            acc[i].w = fmaf(a.x, w0.w, fmaf(a.y, w1.w, fmaf(a.z, w2.w, fmaf(a.w, w3.w, acc[i].w))));
        }
    }

    float4 bs = *(const float4*)(bias + col);
#pragma unroll
    for (int i = 0; i < 8; ++i) {
        int m = row0 + i;
        if (m < N_NODES) {
            float4 v = acc[i];
            v.x = fmaxf(v.x + bs.x, 0.f);
            v.y = fmaxf(v.y + bs.y, 0.f);
            v.z = fmaxf(v.z + bs.z, 0.f);
            v.w = fmaxf(v.w + bs.w, 0.f);
            *(float4*)(C + (size_t)m * D_FEAT + col) = v;
        }
    }
}

// ---- fp32 128x128 GEMM, C = relu(A @ W), safe for C == A (in-place) ------
__global__ __launch_bounds__(256) void gemm128_kernel(
    const float* __restrict__ A,
    const float* __restrict__ W,
    float* __restrict__ C, int M) {
    const int tid  = threadIdx.x;
    const int cg   = tid & 31;
    const int rg   = tid >> 5;
    const int col  = cg << 2;
    const int row0 = blockIdx.x * 64 + rg * 8;

    float4 acc[8];
#pragma unroll
    for (int i = 0; i < 8; ++i) acc[i] = make_float4(0.f, 0.f, 0.f, 0.f);

    const float* arow[8];
#pragma unroll
    for (int i = 0; i < 8; ++i) {
        int m = row0 + i;
        arow[i] = A + (size_t)(m < M ? m : M - 1) * D_FEAT;
    }

    for (int k0 = 0; k0 < D_FEAT; k0 += 4) {
        float4 w0 = *(const float4*)(W + (k0 + 0) * D_FEAT + col);
        float4 w1 = *(const float4*)(W + (k0 + 1) * D_FEAT + col);
        float4 w2 = *(const float4*)(W + (k0 + 2) * D_FEAT + col);
        float4 w3 = *(const float4*)(W + (k0 + 3) * D_FEAT + col);
#pragma unroll
        for (int i = 0; i < 8; ++i) {
            float4 a = *(const float4*)(arow[i] + k0);
            acc[i].x = fmaf(a.x, w0.x, fmaf(a.y, w1.x, fmaf(a.z, w2.x, fmaf(a.w, w3.x, acc[i].x))));
            acc[i].y = fmaf(a.x, w0.y, fmaf(a.y, w1.y, fmaf(a.z, w2.y, fmaf(a.w, w3.y, acc[i].y))));
            acc[i].z = fmaf(a.x, w0.z, fmaf(a.y, w1.z, fmaf(a.z, w2.z, fmaf(a.w, w3.z, acc[i].z))));
            acc[i].w = fmaf(a.x, w0.w, fmaf(a.y, w1.w, fmaf(a.z, w2.w, fmaf(a.w, w3.w, acc[i].w))));
        }
    }

    __syncthreads();   // in-place safety: all A reads complete before any store
#pragma unroll
    for (int i = 0; i < 8; ++i) {
        int m = row0 + i;
        if (m < M) {
            float4 v = acc[i];
            v.x = fmaxf(v.x, 0.f); v.y = fmaxf(v.y, 0.f);
            v.z = fmaxf(v.z, 0.f); v.w = fmaxf(v.w, 0.f);
            *(float4*)(C + (size_t)m * D_FEAT + col) = v;
        }
    }
}

extern "C" void kernel_launch(void* const* d_in, const int* in_sizes, int n_in,
                              void* d_out, int out_size, void* d_ws, size_t ws_size,
                              hipStream_t stream) {
    const float* x           = (const float*)d_in[0];
    const int*   edge_src    = (const int*)d_in[1];
    const int*   edge_dst    = (const int*)d_in[2];
    const float* w_comp      = (const float*)d_in[3];
    const float* bases       = (const float*)d_in[4];
    const float* loop_weight = (const float*)d_in[5];
    const float* h_bias      = (const float*)d_in[6];
    const float* ngnn_w      = (const float*)d_in[7];
    float* out = (float*)d_out;

    // workspace layout
    char* ws = (char*)d_ws;
    size_t off = 0;
    __hip_bfloat162* y = (__hip_bfloat162*)(ws + off);
    off += (size_t)N_NODES * 512 * 2;                                  // 102.4 MB
    int* ebuf = (int*)(ws + off);
    off += (size_t)NB_BUCKETS * BKT_CAP * 4;                           // 28.9 MB
    int* gcursor = (int*)(ws + off);
    off += 1024;                                                       // cursors (aligned pad)
    size_t base_bytes = off;
    __hip_bfloat16* xb = (__hip_bfloat16*)(ws + off);
    size_t xb_bytes = (size_t)N_NODES * D_FEAT * 2;                    // 25.6 MB
    const bool use_bf16_x = (ws_size >= base_bytes + xb_bytes);        // ws_size is constant

    const int GEMM_GRID = (N_NODES + 63) / 64;   // 1563

    // 1) coarse binning
    init_cursor_kernel<<<1, 256, 0, stream>>>(gcursor);
    bin_kernel<<<(RE + BIN_CHUNK - 1) / BIN_CHUNK, BIN_TPB, 0, stream>>>(
        edge_src, edge_dst, gcursor, ebuf);

    // 2) aggregate -> y (bf16, basis-combined, deg-normalized)
    if (use_bf16_x) {
        xcvt_kernel<<<(N_NODES * D_FEAT / 2 + 255) / 256, 256, 0, stream>>>(
            x, (__hip_bfloat162*)xb);
        agg_kernel<true><<<NB_BUCKETS * 32, AGG_TPB, 0, stream>>>(
            x, xb, w_comp, gcursor, ebuf, y);
    } else {
        agg_kernel<false><<<NB_BUCKETS * 32, AGG_TPB, 0, stream>>>(
            x, nullptr, w_comp, gcursor, ebuf, y);
    }

    // 3) out = relu([y|x] @ [bases;loop_w] + bias)
    gemm_big_kernel<<<GEMM_GRID, 256, 0, stream>>>(
        (const uint*)y, x, bases, loop_weight, h_bias, out);

    // 4) NGNN in-place on d_out
    gemm128_kernel<<<GEMM_GRID, 256, 0, stream>>>(out, ngnn_w, out, N_NODES);
    gemm128_kernel<<<GEMM_GRID, 256, 0, stream>>>(out, ngnn_w + D_FEAT * D_FEAT, out, N_NODES);
}

// Round 5
// 1253.237 us; speedup vs baseline: 13.9595x; 13.9595x over previous
//
#include <hip/hip_runtime.h>
#include <hip/hip_bf16.h>

#define N_NODES 100000
#define R_REL   8
#define E_EDGES 800000
#define D_FEAT  128
#define B_BASES 4
#define RN      (R_REL * N_NODES)          // 800000 keys (key = dst*8 + r)
#define RE      (R_REL * E_EDGES)          // 6.4M edges

// radix partition: 196 coarse buckets of 512 dst nodes each
#define NBKT    196
#define BKT_CAP 36864                      // mean 32768, +22 sigma slack
#define P1_TPB  256
#define P1_EPT  32
#define P1_CHUNK (P1_TPB * P1_EPT)         // 8192 edges / WG
#define P1_NWG  ((RE + P1_CHUNK - 1) / P1_CHUNK)   // 782

__global__ __launch_bounds__(256) void init_cursor_kernel(int* __restrict__ gcursor) {
    int t = threadIdx.x;
    if (t < NBKT) gcursor[t] = t * BKT_CAP;
}

// ---- pass 1: partition edges into coarse dst-buckets (coalesced writes) ---
// record = src(17b) | dst_low(9b)<<17 | r(3b)<<26
__global__ __launch_bounds__(256) void p1_kernel(
    const int* __restrict__ src, const int* __restrict__ dst,
    int* __restrict__ gcursor, int* __restrict__ ebuf2) {
    __shared__ int hist[NBKT];
    __shared__ int cnt2[NBKT];
    __shared__ int basebkt[NBKT];
    __shared__ int lofs[256];              // scan array (196 padded to 256)
    __shared__ int recs[P1_CHUNK];         // 32 KB
    __shared__ unsigned char bb[P1_CHUNK]; // 8 KB: bucket id per slot
    int t = threadIdx.x;
    for (int i = t; i < NBKT; i += 256) { hist[i] = 0; cnt2[i] = 0; }
    __syncthreads();

    int e0 = blockIdx.x * P1_CHUNK;
    int rec[P1_EPT];
    int bkt[P1_EPT];
#pragma unroll
    for (int i = 0; i < P1_EPT; ++i) {
        int e = e0 + i * P1_TPB + t;       // coalesced
        if (e < RE) {
            int d = dst[e];
            int s = src[e];
            int r = e / E_EDGES;           // magic-mul division
            bkt[i] = d >> 9;
            rec[i] = s | ((d & 511) << 17) | (r << 26);
            atomicAdd(&hist[bkt[i]], 1);   // int LDS atomic: native ds_add
        } else bkt[i] = -1;
    }
    __syncthreads();

    // exclusive scan of hist over 256 slots (Hillis-Steele)
    int hv = (t < NBKT) ? hist[t] : 0;
    lofs[t] = hv;
    __syncthreads();
    int val = hv;
    for (int off = 1; off < 256; off <<= 1) {
        int yv = (t >= off) ? lofs[t - off] : 0;
        __syncthreads();
        val += yv;
        lofs[t] = val;
        __syncthreads();
    }
    int total = lofs[NBKT - 1];            // inclusive sum = valid edges in chunk
    __syncthreads();
    lofs[t] = val - hv;                    // exclusive
    if (t < NBKT) basebkt[t] = (hv > 0) ? atomicAdd(&gcursor[t], hv) : 0;
    __syncthreads();

    // reorder records into bucket-contiguous LDS slots
#pragma unroll
    for (int i = 0; i < P1_EPT; ++i) {
        if (bkt[i] >= 0) {
            int p = lofs[bkt[i]] + atomicAdd(&cnt2[bkt[i]], 1);
            recs[p] = rec[i];
            bb[p] = (unsigned char)bkt[i];
        }
    }
    __syncthreads();

    // coalesced-ish writeout: consecutive i are mostly the same bucket run
    for (int i = t; i < total; i += 256) {
        int b = bb[i];
        int p2 = basebkt[b] + (i - lofs[b]);
        if (p2 < (b + 1) * BKT_CAP) ebuf2[p2] = recs[i];
    }
}

// ---- pass 2: per-bucket CSR finalize (degrees, offsets, scatter) ----------
// one WG per bucket; all-int LDS atomics; produces exact offsets[] + ebuf[]
__global__ __launch_bounds__(1024) void p2_kernel(
    const int* __restrict__ gcursor,
    const int* __restrict__ ebuf2,
    int* __restrict__ offsets,             // [RN+1]
    int* __restrict__ ebuf) {
    __shared__ int cursors[4096];          // 16 KB: per-(node,r) within bucket
    __shared__ int aux[1024];              // 4 KB scan aux
    const int t = threadIdx.x;
    const int bucket = blockIdx.x;

    // 1) bucket base = exclusive prefix of per-bucket counts (all WGs redo this tiny scan)
    int c = 0;
    if (t < NBKT) {
        c = gcursor[t] - t * BKT_CAP;
        if (c > BKT_CAP) c = BKT_CAP;
    }
    if (t < 256) aux[t] = c;
    __syncthreads();
    int vsc = (t < 256) ? aux[t] : 0;
    int run = vsc;
    for (int off = 1; off < 256; off <<= 1) {
        int yv = (t >= off && t < 256) ? aux[t - off] : 0;
        __syncthreads();
        if (t < 256) { run += yv; aux[t] = run; }
        __syncthreads();
    }
    int mybase = (bucket == 0) ? 0 : aux[bucket - 1];   // inclusive scan → exclusive base
    int mycnt  = aux[bucket] - mybase;
    __syncthreads();

    // 2) zero cursors
    for (int i = t; i < 4096; i += 1024) cursors[i] = 0;
    __syncthreads();

    // 3) degree histogram over this bucket's records
    const int* brec = ebuf2 + (size_t)bucket * BKT_CAP;
    for (int i = t; i < mycnt; i += 1024) {
        int rec = brec[i];
        int key = ((rec >> 17) & 511) * 8 + ((rec >> 26) & 7);
        atomicAdd(&cursors[key], 1);
    }
    __syncthreads();

    // 4) exclusive scan of cursors[4096]: thread owns 4 consecutive
    int k0 = t * 4;
    int c0 = cursors[k0], c1 = cursors[k0 + 1], c2 = cursors[k0 + 2], c3 = cursors[k0 + 3];
    int s0 = c0, s1 = s0 + c1, s2 = s1 + c2, s3 = s2 + c3;
    aux[t] = s3;
    __syncthreads();
    int vv = s3;
    for (int off = 1; off < 1024; off <<= 1) {
        int yv = (t >= off) ? aux[t - off] : 0;
        __syncthreads();
        vv += yv;
        aux[t] = vv;
        __syncthreads();
    }
    int texcl = vv - s3;
    int g0 = mybase + texcl;
    int g1 = g0 + c0, g2 = g1 + c1, g3 = g2 + c2;

    // 5) write global offsets (guarded; bucket 195 writes the RN sentinel = RE)
    int idx = bucket * 4096 + k0;
    if (idx + 0 <= RN) offsets[idx + 0] = g0;
    if (idx + 1 <= RN) offsets[idx + 1] = g1;
    if (idx + 2 <= RN) offsets[idx + 2] = g2;
    if (idx + 3 <= RN) offsets[idx + 3] = g3;
    __syncthreads();
    cursors[k0 + 0] = g0;                  // claim cursors, absolute ebuf positions
    cursors[k0 + 1] = g1;
    cursors[k0 + 2] = g2;
    cursors[k0 + 3] = g3;
    __syncthreads();

    // 6) scatter src ids to exact CSR slots (stores land in a ~128 KB L2 window)
    for (int i = t; i < mycnt; i += 1024) {
        int rec = brec[i];
        int key = ((rec >> 17) & 511) * 8 + ((rec >> 26) & 7);
        int pos = atomicAdd(&cursors[key], 1);   // native ds_add_rtn_u32
        ebuf[pos] = rec & 0x1FFFF;
    }
}

// ---- fused gather: all 8 relations -> 4 basis-combined bf16 outputs -------
__global__ __launch_bounds__(256) void gather_kernel(
    const float* __restrict__ x,
    const int*   __restrict__ offsets,
    const int*   __restrict__ ebuf,
    const float* __restrict__ w_comp,
    __hip_bfloat162* __restrict__ y) {     // [N][256] bf162
    int node = (blockIdx.x << 2) + (threadIdx.x >> 6);
    if (node >= N_NODES) return;
    int lane = threadIdx.x & 63;
    const float* xp = x + 2 * lane;

    float2 acc[R_REL];
    float  inv[R_REL];
    int segbase = node * R_REL;
#pragma unroll
    for (int r = 0; r < R_REL; ++r) {
        int beg = offsets[segbase + r];
        int end = offsets[segbase + r + 1];
        int d = end - beg;
        inv[r] = 1.0f / (float)(d > 1 ? d : 1);
        float ax = 0.f, ay = 0.f;
        int i = beg;
        for (; i + 3 < end; i += 4) {
            int s0 = ebuf[i], s1 = ebuf[i + 1], s2 = ebuf[i + 2], s3 = ebuf[i + 3];
            float2 a = *(const float2*)(xp + (size_t)s0 * D_FEAT);
            float2 b = *(const float2*)(xp + (size_t)s1 * D_FEAT);
            float2 c = *(const float2*)(xp + (size_t)s2 * D_FEAT);
            float2 d2 = *(const float2*)(xp + (size_t)s3 * D_FEAT);
            ax += (a.x + b.x) + (c.x + d2.x);
            ay += (a.y + b.y) + (c.y + d2.y);
        }
        for (; i < end; ++i) {
            int s = ebuf[i];
            float2 a = *(const float2*)(xp + (size_t)s * D_FEAT);
            ax += a.x; ay += a.y;
        }
        acc[r] = make_float2(ax, ay);
    }

#pragma unroll
    for (int b = 0; b < B_BASES; ++b) {
        float sx = 0.f, sy = 0.f;
#pragma unroll
        for (int r = 0; r < R_REL; ++r) {
            float coef = w_comp[r * B_BASES + b] * inv[r];
            sx = fmaf(coef, acc[r].x, sx);
            sy = fmaf(coef, acc[r].y, sy);
        }
        y[(size_t)node * 256 + b * 64 + lane] = __float22bfloat162_rn(make_float2(sx, sy));
    }
}

// ---- big GEMM: out = relu([y(bf16) | x] @ [bases ; loop_weight] + bias) ---
__global__ __launch_bounds__(256) void gemm_big_kernel(
    const uint* __restrict__ y,            // [N][256] packed bf16 pairs
    const float* __restrict__ x,
    const float* __restrict__ bases,       // [512][128] stacked
    const float* __restrict__ loopw,       // [128][128]
    const float* __restrict__ bias,
    float* __restrict__ C) {
    const int tid  = threadIdx.x;
    const int cg   = tid & 31;
    const int rg   = tid >> 5;
    const int col  = cg << 2;
    const int row0 = blockIdx.x * 64 + rg * 8;

    float4 acc[8];
#pragma unroll
    for (int i = 0; i < 8; ++i) acc[i] = make_float4(0.f, 0.f, 0.f, 0.f);

    int rowc[8];
#pragma unroll
    for (int i = 0; i < 8; ++i) {
        int m = row0 + i;
        rowc[i] = m < N_NODES ? m : N_NODES - 1;
    }

    for (int k0 = 0; k0 < 512; k0 += 4) {
        float4 w0 = *(const float4*)(bases + (k0 + 0) * D_FEAT + col);
        float4 w1 = *(const float4*)(bases + (k0 + 1) * D_FEAT + col);
        float4 w2 = *(const float4*)(bases + (k0 + 2) * D_FEAT + col);
        float4 w3 = *(const float4*)(bases + (k0 + 3) * D_FEAT + col);
#pragma unroll
        for (int i = 0; i < 8; ++i) {
            uint2 u = *(const uint2*)(y + (size_t)rowc[i] * 256 + (k0 >> 1));
            float a0 = __uint_as_float(u.x << 16);
            float a1 = __uint_as_float(u.x & 0xFFFF0000u);
            float a2 = __uint_as_float(u.y << 16);
            float a3 = __uint_as_float(u.y & 0xFFFF0000u);
            acc[i].x = fmaf(a0, w0.x, fmaf(a1, w1.x, fmaf(a2, w2.x, fmaf(a3, w3.x, acc[i].x))));
            acc[i].y = fmaf(a0, w0.y, fmaf(a1, w1.y, fmaf(a2, w2.y, fmaf(a3, w3.y, acc[i].y))));
            acc[i].z = fmaf(a0, w0.z, fmaf(a1, w1.z, fmaf(a2, w2.z, fmaf(a3, w3.z, acc[i].z))));
            acc[i].w = fmaf(a0, w0.w, fmaf(a1, w1.w, fmaf(a2, w2.w, fmaf(a3, w3.w, acc[i].w))));
        }
    }
    for (int k0 = 0; k0 < 128; k0 += 4) {
        float4 w0 = *(const float4*)(loopw + (k0 + 0) * D_FEAT + col);
        float4 w1 = *(const float4*)(loopw + (k0 + 1) * D_FEAT + col);
        float4 w2 = *(const float4*)(loopw + (k0 + 2) * D_FEAT + col);
        float4 w3 = *(const float4*)(loopw + (k0 + 3) * D_FEAT + col);
#pragma unroll
        for (int i = 0; i < 8; ++i) {
            float4 a = *(const float4*)(x + (size_t)rowc[i] * D_FEAT + k0);
            acc[i].x = fmaf(a.x, w0.x, fmaf(a.y, w1.x, fmaf(a.z, w2.x, fmaf(a.w, w3.x, acc[i].x))));
            acc[i].y = fmaf(a.x, w0.y, fmaf(a.y, w1.y, fmaf(a.z, w2.y, fmaf(a.w, w3.y, acc[i].y))));
            acc[i].z = fmaf(a.x, w0.z, fmaf(a.y, w1.z, fmaf(a.z, w2.z, fmaf(a.w, w3.z, acc[i].z))));
            acc[i].w = fmaf(a.x, w0.w, fmaf(a.y, w1.w, fmaf(a.z, w2.w, fmaf(a.w, w3.w, acc[i].w))));
        }
    }

    float4 bs = *(const float4*)(bias + col);
#pragma unroll
    for (int i = 0; i < 8; ++i) {
        int m = row0 + i;
        if (m < N_NODES) {
            float4 v = acc[i];
            v.x = fmaxf(v.x + bs.x, 0.f);
            v.y = fmaxf(v.y + bs.y, 0.f);
            v.z = fmaxf(v.z + bs.z, 0.f);
            v.w = fmaxf(v.w + bs.w, 0.f);
            *(float4*)(C + (size_t)m * D_FEAT + col) = v;
        }
    }
}

// ---- fp32 128x128 GEMM, C = relu(A @ W), safe for C == A (in-place) ------
__global__ __launch_bounds__(256) void gemm128_kernel(
    const float* __restrict__ A,
    const float* __restrict__ W,
    float* __restrict__ C, int M) {
    const int tid  = threadIdx.x;
    const int cg   = tid & 31;
    const int rg   = tid >> 5;
    const int col  = cg << 2;
    const int row0 = blockIdx.x * 64 + rg * 8;

    float4 acc[8];
#pragma unroll
    for (int i = 0; i < 8; ++i) acc[i] = make_float4(0.f, 0.f, 0.f, 0.f);

    const float* arow[8];
#pragma unroll
    for (int i = 0; i < 8; ++i) {
        int m = row0 + i;
        arow[i] = A + (size_t)(m < M ? m : M - 1) * D_FEAT;
    }

    for (int k0 = 0; k0 < D_FEAT; k0 += 4) {
        float4 w0 = *(const float4*)(W + (k0 + 0) * D_FEAT + col);
        float4 w1 = *(const float4*)(W + (k0 + 1) * D_FEAT + col);
        float4 w2 = *(const float4*)(W + (k0 + 2) * D_FEAT + col);
        float4 w3 = *(const float4*)(W + (k0 + 3) * D_FEAT + col);
#pragma unroll
        for (int i = 0; i < 8; ++i) {
            float4 a = *(const float4*)(arow[i] + k0);
            acc[i].x = fmaf(a.x, w0.x, fmaf(a.y, w1.x, fmaf(a.z, w2.x, fmaf(a.w, w3.x, acc[i].x))));
            acc[i].y = fmaf(a.x, w0.y, fmaf(a.y, w1.y, fmaf(a.z, w2.y, fmaf(a.w, w3.y, acc[i].y))));
            acc[i].z = fmaf(a.x, w0.z, fmaf(a.y, w1.z, fmaf(a.z, w2.z, fmaf(a.w, w3.z, acc[i].z))));
            acc[i].w = fmaf(a.x, w0.w, fmaf(a.y, w1.w, fmaf(a.z, w2.w, fmaf(a.w, w3.w, acc[i].w))));
        }
    }

    __syncthreads();   // in-place safety: all A reads complete before any store
#pragma unroll
    for (int i = 0; i < 8; ++i) {
        int m = row0 + i;
        if (m < M) {
            float4 v = acc[i];
            v.x = fmaxf(v.x, 0.f); v.y = fmaxf(v.y, 0.f);
            v.z = fmaxf(v.z, 0.f); v.w = fmaxf(v.w, 0.f);
            *(float4*)(C + (size_t)m * D_FEAT + col) = v;
        }
    }
}

extern "C" void kernel_launch(void* const* d_in, const int* in_sizes, int n_in,
                              void* d_out, int out_size, void* d_ws, size_t ws_size,
                              hipStream_t stream) {
    const float* x           = (const float*)d_in[0];
    const int*   edge_src    = (const int*)d_in[1];
    const int*   edge_dst    = (const int*)d_in[2];
    const float* w_comp      = (const float*)d_in[3];
    const float* bases       = (const float*)d_in[4];
    const float* loop_weight = (const float*)d_in[5];
    const float* h_bias      = (const float*)d_in[6];
    const float* ngnn_w      = (const float*)d_in[7];
    float* out = (float*)d_out;

    // workspace layout (~131 MB; ebuf2 aliases y, which is dead until gather)
    char* ws = (char*)d_ws;
    size_t off = 0;
    __hip_bfloat162* y = (__hip_bfloat162*)(ws + off);
    int* ebuf2 = (int*)(ws + off);                 // [NBKT*BKT_CAP] = 28.9 MB, inside y
    off += (size_t)N_NODES * 512 * 2;              // 102.4 MB
    int* ebuf = (int*)(ws + off);
    off += (size_t)RE * 4;                         // 25.6 MB
    int* offsets = (int*)(ws + off);
    off += ((size_t)RN + 1) * 4;                   // 3.2 MB
    int* gcursor = (int*)(ws + off);
    off += 1024;

    const int GEMM_GRID = (N_NODES + 63) / 64;     // 1563

    // 1) radix CSR build (replaces count/scan1/scan2/scan3/bucket)
    init_cursor_kernel<<<1, 256, 0, stream>>>(gcursor);
    p1_kernel<<<P1_NWG, P1_TPB, 0, stream>>>(edge_src, edge_dst, gcursor, ebuf2);
    p2_kernel<<<NBKT, 1024, 0, stream>>>(gcursor, ebuf2, offsets, ebuf);

    // 2) fused gather -> y (bf16, basis-combined, deg-normalized)
    gather_kernel<<<(N_NODES + 3) / 4, 256, 0, stream>>>(x, offsets, ebuf, w_comp, y);

    // 3) out = relu([y|x] @ [bases;loop_w] + bias)
    gemm_big_kernel<<<GEMM_GRID, 256, 0, stream>>>(
        (const uint*)y, x, bases, loop_weight, h_bias, out);

    // 4) NGNN in-place on d_out
    gemm128_kernel<<<GEMM_GRID, 256, 0, stream>>>(out, ngnn_w, out, N_NODES);
    gemm128_kernel<<<GEMM_GRID, 256, 0, stream>>>(out, ngnn_w + D_FEAT * D_FEAT, out, N_NODES);
}

// Round 6
// 921.282 us; speedup vs baseline: 18.9894x; 1.3603x over previous
//
#include <hip/hip_runtime.h>
#include <hip/hip_bf16.h>

#define N_NODES 100000
#define R_REL   8
#define E_EDGES 800000
#define D_FEAT  128
#define B_BASES 4
#define RN      (R_REL * N_NODES)          // 800000 keys (key = dst*8 + r)
#define RE      (R_REL * E_EDGES)          // 6.4M edges

// radix partition: 784 coarse buckets of 128 dst nodes each
#define NBKT    784
#define BKT_CAP 9216                       // mean 8163, +11 sigma slack
#define P1_TPB  256
#define P1_EPT  32
#define P1_CHUNK (P1_TPB * P1_EPT)         // 8192 edges / WG
#define P1_NWG  ((RE + P1_CHUNK - 1) / P1_CHUNK)   // 782

typedef __attribute__((ext_vector_type(8))) short short8;
typedef __attribute__((ext_vector_type(4))) float floatx4;

__global__ __launch_bounds__(1024) void init_cursor_kernel(int* __restrict__ gcursor) {
    int t = threadIdx.x;
    if (t < NBKT) gcursor[t] = t * BKT_CAP;
}

// x (fp32) -> xb (bf162 pairs)
__global__ __launch_bounds__(256) void xcvt_kernel(
    const float* __restrict__ x, uint* __restrict__ xb) {
    int i = blockIdx.x * 256 + threadIdx.x;          // over N*64 pairs
    if (i >= N_NODES * 64) return;
    float2 v = *(const float2*)(x + 2 * (size_t)i);
    __hip_bfloat162 h = __float22bfloat162_rn(v);
    xb[i] = *(uint*)&h;
}

// wT[n][k] = bf16( k<512 ? bases[k][n] : loop_weight[k-512][n] )
__global__ __launch_bounds__(256) void wcvt_kernel(
    const float* __restrict__ bases, const float* __restrict__ loopw,
    unsigned short* __restrict__ wT) {
    int idx = blockIdx.x * 256 + threadIdx.x;        // over 128*640
    if (idx >= 128 * 640) return;
    int n = idx / 640, k = idx % 640;
    float v = (k < 512) ? bases[(size_t)k * 128 + n] : loopw[(size_t)(k - 512) * 128 + n];
    __hip_bfloat16 h = __float2bfloat16(v);
    wT[idx] = *(unsigned short*)&h;
}

// ---- pass 1: partition edges into coarse dst-buckets (coalesced writes) ---
// record = src(17b) | dst_low(7b)<<17 | r(3b)<<24
__global__ __launch_bounds__(256) void p1_kernel(
    const int* __restrict__ src, const int* __restrict__ dst,
    int* __restrict__ gcursor, int* __restrict__ ebuf2) {
    __shared__ int hist[NBKT];
    __shared__ int cnt2[NBKT];
    __shared__ int basebkt[NBKT];
    __shared__ int lofs[NBKT];
    __shared__ int aux[256];
    __shared__ int recs[P1_CHUNK];           // 32 KB
    __shared__ unsigned short bb[P1_CHUNK];  // 16 KB
    int t = threadIdx.x;
    for (int i = t; i < NBKT; i += 256) { hist[i] = 0; cnt2[i] = 0; }
    __syncthreads();

    int e0 = blockIdx.x * P1_CHUNK;
    int rec[P1_EPT];
    int bkt[P1_EPT];
#pragma unroll
    for (int i = 0; i < P1_EPT; ++i) {
        int e = e0 + i * P1_TPB + t;         // coalesced
        if (e < RE) {
            int d = dst[e];
            int s = src[e];
            int r = e / E_EDGES;             // magic-mul division
            bkt[i] = d >> 7;
            rec[i] = s | ((d & 127) << 17) | (r << 24);
            atomicAdd(&hist[bkt[i]], 1);     // native int ds_add
        } else bkt[i] = -1;
    }
    __syncthreads();

    // exclusive scan of hist[784]: 4 consecutive per thread + Hillis-Steele on aux
    int k0 = t * 4;
    int c0 = (k0 + 0 < NBKT) ? hist[k0 + 0] : 0;
    int c1 = (k0 + 1 < NBKT) ? hist[k0 + 1] : 0;
    int c2 = (k0 + 2 < NBKT) ? hist[k0 + 2] : 0;
    int c3 = (k0 + 3 < NBKT) ? hist[k0 + 3] : 0;
    int s1 = c0 + c1, s2 = s1 + c2, s3 = s2 + c3;
    aux[t] = s3;
    __syncthreads();
    int vv = s3;
    for (int off = 1; off < 256; off <<= 1) {
        int yv = (t >= off) ? aux[t - off] : 0;
        __syncthreads();
        vv += yv;
        aux[t] = vv;
        __syncthreads();
    }
    int total = aux[255];
    int texcl = vv - s3;
    if (k0 + 0 < NBKT) lofs[k0 + 0] = texcl;
    if (k0 + 1 < NBKT) lofs[k0 + 1] = texcl + c0;
    if (k0 + 2 < NBKT) lofs[k0 + 2] = texcl + s1;
    if (k0 + 3 < NBKT) lofs[k0 + 3] = texcl + s2;
    __syncthreads();
    for (int i = t; i < NBKT; i += 256) {
        int hv = hist[i];
        basebkt[i] = (hv > 0) ? atomicAdd(&gcursor[i], hv) : 0;
    }
    __syncthreads();

    // reorder records into bucket-contiguous LDS slots
#pragma unroll
    for (int i = 0; i < P1_EPT; ++i) {
        if (bkt[i] >= 0) {
            int p = lofs[bkt[i]] + atomicAdd(&cnt2[bkt[i]], 1);
            recs[p] = rec[i];
            bb[p] = (unsigned short)bkt[i];
        }
    }
    __syncthreads();

    // writeout: consecutive i are mostly same-bucket runs
    for (int i = t; i < total; i += 256) {
        int b = bb[i];
        int p2 = basebkt[b] + (i - lofs[b]);
        if (p2 < (b + 1) * BKT_CAP) ebuf2[p2] = recs[i];
    }
}

// ---- pass 2: per-bucket CSR finalize; 1024 thr, thread t owns key t -------
__global__ __launch_bounds__(1024) void p2_kernel(
    const int* __restrict__ gcursor,
    const int* __restrict__ ebuf2,
    int* __restrict__ offsets,               // [RN+1]
    int* __restrict__ ebuf) {
    __shared__ int cursors[1024];
    __shared__ int aux[1024];
    const int t = threadIdx.x;
    const int bucket = blockIdx.x;

    // bucket base = exclusive prefix of per-bucket counts
    int c = 0;
    if (t < NBKT) {
        c = gcursor[t] - t * BKT_CAP;
        if (c > BKT_CAP) c = BKT_CAP;
    }
    aux[t] = c;
    __syncthreads();
    int vv = c;
    for (int off = 1; off < 1024; off <<= 1) {
        int yv = (t >= off) ? aux[t - off] : 0;
        __syncthreads();
        vv += yv;
        aux[t] = vv;
        __syncthreads();
    }
    int mybase = (bucket == 0) ? 0 : aux[bucket - 1];
    int mycnt  = aux[bucket] - mybase;
    __syncthreads();

    cursors[t] = 0;
    __syncthreads();

    // degree histogram
    const int* brec = ebuf2 + (size_t)bucket * BKT_CAP;
    for (int i = t; i < mycnt; i += 1024) {
        int rec = brec[i];
        int key = ((rec >> 17) & 127) * 8 + ((rec >> 24) & 7);
        atomicAdd(&cursors[key], 1);
    }
    __syncthreads();

    // exclusive scan of 1024 degrees
    int deg = cursors[t];
    aux[t] = deg;
    __syncthreads();
    int iv = deg;
    for (int off = 1; off < 1024; off <<= 1) {
        int yv = (t >= off) ? aux[t - off] : 0;
        __syncthreads();
        iv += yv;
        aux[t] = iv;
        __syncthreads();
    }
    int g0 = mybase + iv - deg;

    int idx = bucket * 1024 + t;             // == node*8 + r globally
    if (idx <= RN) offsets[idx] = g0;        // bucket 781/t=256 writes sentinel RE
    __syncthreads();
    cursors[t] = g0;
    __syncthreads();

    // scatter src ids to exact CSR slots (stores land in a ~32 KB L2 window)
    for (int i = t; i < mycnt; i += 1024) {
        int rec = brec[i];
        int key = ((rec >> 17) & 127) * 8 + ((rec >> 24) & 7);
        int pos = atomicAdd(&cursors[key], 1);   // ds_add_rtn_u32
        ebuf[pos] = rec & 0x1FFFF;
    }
}

// ---- fused gather: all 8 relations -> 4 basis-combined bf16 outputs -------
template <bool XB>
__global__ __launch_bounds__(256) void gather_kernel(
    const float* __restrict__ x,
    const uint*  __restrict__ xb,          // [N][64] bf162 pairs
    const int*   __restrict__ offsets,
    const int*   __restrict__ ebuf,
    const float* __restrict__ w_comp,
    __hip_bfloat162* __restrict__ y) {     // [N][256] bf162
    int node = (blockIdx.x << 2) + (threadIdx.x >> 6);
    if (node >= N_NODES) return;
    int lane = threadIdx.x & 63;
    const float* xp = x + 2 * lane;
    const uint*  xbp = xb + lane;

    float2 acc[R_REL];
    float  inv[R_REL];
    int segbase = node * R_REL;
#pragma unroll
    for (int r = 0; r < R_REL; ++r) {
        int beg = offsets[segbase + r];
        int end = offsets[segbase + r + 1];
        int d = end - beg;
        inv[r] = 1.0f / (float)(d > 1 ? d : 1);
        float ax = 0.f, ay = 0.f;
        int i = beg;
        for (; i + 3 < end; i += 4) {
            int s0 = ebuf[i], s1 = ebuf[i + 1], s2 = ebuf[i + 2], s3 = ebuf[i + 3];
            if (XB) {
                uint u0 = xbp[(size_t)s0 * 64];
                uint u1 = xbp[(size_t)s1 * 64];
                uint u2 = xbp[(size_t)s2 * 64];
                uint u3 = xbp[(size_t)s3 * 64];
                ax += (__uint_as_float(u0 << 16) + __uint_as_float(u1 << 16))
                    + (__uint_as_float(u2 << 16) + __uint_as_float(u3 << 16));
                ay += (__uint_as_float(u0 & 0xFFFF0000u) + __uint_as_float(u1 & 0xFFFF0000u))
                    + (__uint_as_float(u2 & 0xFFFF0000u) + __uint_as_float(u3 & 0xFFFF0000u));
            } else {
                float2 a = *(const float2*)(xp + (size_t)s0 * D_FEAT);
                float2 b = *(const float2*)(xp + (size_t)s1 * D_FEAT);
                float2 cc = *(const float2*)(xp + (size_t)s2 * D_FEAT);
                float2 d2 = *(const float2*)(xp + (size_t)s3 * D_FEAT);
                ax += (a.x + b.x) + (cc.x + d2.x);
                ay += (a.y + b.y) + (cc.y + d2.y);
            }
        }
        for (; i < end; ++i) {
            int s = ebuf[i];
            if (XB) {
                uint u = xbp[(size_t)s * 64];
                ax += __uint_as_float(u << 16);
                ay += __uint_as_float(u & 0xFFFF0000u);
            } else {
                float2 a = *(const float2*)(xp + (size_t)s * D_FEAT);
                ax += a.x; ay += a.y;
            }
        }
        acc[r] = make_float2(ax, ay);
    }

#pragma unroll
    for (int b = 0; b < B_BASES; ++b) {
        float sx = 0.f, sy = 0.f;
#pragma unroll
        for (int r = 0; r < R_REL; ++r) {
            float coef = w_comp[r * B_BASES + b] * inv[r];
            sx = fmaf(coef, acc[r].x, sx);
            sy = fmaf(coef, acc[r].y, sy);
        }
        y[(size_t)node * 256 + b * 64 + lane] = __float22bfloat162_rn(make_float2(sx, sy));
    }
}

// ---- MFMA GEMM: out = relu([y | bf16(x)] @ wT^T + bias), K=640 ------------
// 64 rows/block, 4 waves; wave = one 16-row tile x 8 col-tiles of 16.
// frags: A[m=lane&15][k=quad*8+j], B[n=lane&15][k=quad*8+j] (from wT),
// D[row=quad*4+reg][col=lane&15]  (verified layouts, m89/m120)
__global__ __launch_bounds__(256) void gemm_big_mfma(
    const short* __restrict__ y,           // [N][512] bf16
    const float* __restrict__ x,           // [N][128] fp32
    const unsigned short* __restrict__ wT, // [128][640] bf16
    const float* __restrict__ bias,
    float* __restrict__ C) {
    const int wave = threadIdx.x >> 6;
    const int lane = threadIdx.x & 63;
    const int quad = lane >> 4;
    const int l16  = lane & 15;
    const int row0 = blockIdx.x * 64 + wave * 16;
    int arow = row0 + l16;
    if (arow >= N_NODES) arow = N_NODES - 1;

    floatx4 acc[8];
#pragma unroll
    for (int nt = 0; nt < 8; ++nt) acc[nt] = (floatx4){0.f, 0.f, 0.f, 0.f};

    const short* yrow = y + (size_t)arow * 512;
    const float* xrow = x + (size_t)arow * 128;
    const int koff = quad * 8;

    // phase 1: K=512 from y
    for (int ks = 0; ks < 16; ++ks) {
        int k0 = ks * 32 + koff;
        short8 a = *(const short8*)(yrow + k0);
#pragma unroll
        for (int nt = 0; nt < 8; ++nt) {
            int n = nt * 16 + l16;
            short8 b = *(const short8*)((const short*)wT + (size_t)n * 640 + k0);
            acc[nt] = __builtin_amdgcn_mfma_f32_16x16x32_bf16(a, b, acc[nt], 0, 0, 0);
        }
    }
    // phase 2: K=128 from x, converted to bf16 in registers
#pragma unroll
    for (int ks = 0; ks < 4; ++ks) {
        int k0 = ks * 32 + koff;
        float4 fa = *(const float4*)(xrow + k0);
        float4 fb = *(const float4*)(xrow + k0 + 4);
        union { short8 s; uint u[4]; } ua;
        __hip_bfloat162 h0 = __float22bfloat162_rn(make_float2(fa.x, fa.y));
        __hip_bfloat162 h1 = __float22bfloat162_rn(make_float2(fa.z, fa.w));
        __hip_bfloat162 h2 = __float22bfloat162_rn(make_float2(fb.x, fb.y));
        __hip_bfloat162 h3 = __float22bfloat162_rn(make_float2(fb.z, fb.w));
        ua.u[0] = *(uint*)&h0; ua.u[1] = *(uint*)&h1;
        ua.u[2] = *(uint*)&h2; ua.u[3] = *(uint*)&h3;
#pragma unroll
        for (int nt = 0; nt < 8; ++nt) {
            int n = nt * 16 + l16;
            short8 b = *(const short8*)((const short*)wT + (size_t)n * 640 + 512 + k0);
            acc[nt] = __builtin_amdgcn_mfma_f32_16x16x32_bf16(ua.s, b, acc[nt], 0, 0, 0);
        }
    }

    // epilogue
#pragma unroll
    for (int nt = 0; nt < 8; ++nt) {
        int n = nt * 16 + l16;
        float bs = bias[n];
#pragma unroll
        for (int i = 0; i < 4; ++i) {
            int m = row0 + quad * 4 + i;
            if (m < N_NODES)
                C[(size_t)m * D_FEAT + n] = fmaxf(acc[nt][i] + bs, 0.f);
        }
    }
}

// ---- fp32 128x128 GEMM, C = relu(A @ W), safe for C == A (in-place) ------
__global__ __launch_bounds__(256) void gemm128_kernel(
    const float* __restrict__ A,
    const float* __restrict__ W,
    float* __restrict__ C, int M) {
    const int tid  = threadIdx.x;
    const int cg   = tid & 31;
    const int rg   = tid >> 5;
    const int col  = cg << 2;
    const int row0 = blockIdx.x * 64 + rg * 8;

    float4 acc[8];
#pragma unroll
    for (int i = 0; i < 8; ++i) acc[i] = make_float4(0.f, 0.f, 0.f, 0.f);

    const float* arow[8];
#pragma unroll
    for (int i = 0; i < 8; ++i) {
        int m = row0 + i;
        arow[i] = A + (size_t)(m < M ? m : M - 1) * D_FEAT;
    }

    for (int k0 = 0; k0 < D_FEAT; k0 += 4) {
        float4 w0 = *(const float4*)(W + (k0 + 0) * D_FEAT + col);
        float4 w1 = *(const float4*)(W + (k0 + 1) * D_FEAT + col);
        float4 w2 = *(const float4*)(W + (k0 + 2) * D_FEAT + col);
        float4 w3 = *(const float4*)(W + (k0 + 3) * D_FEAT + col);
#pragma unroll
        for (int i = 0; i < 8; ++i) {
            float4 a = *(const float4*)(arow[i] + k0);
            acc[i].x = fmaf(a.x, w0.x, fmaf(a.y, w1.x, fmaf(a.z, w2.x, fmaf(a.w, w3.x, acc[i].x))));
            acc[i].y = fmaf(a.x, w0.y, fmaf(a.y, w1.y, fmaf(a.z, w2.y, fmaf(a.w, w3.y, acc[i].y))));
            acc[i].z = fmaf(a.x, w0.z, fmaf(a.y, w1.z, fmaf(a.z, w2.z, fmaf(a.w, w3.z, acc[i].z))));
            acc[i].w = fmaf(a.x, w0.w, fmaf(a.y, w1.w, fmaf(a.z, w2.w, fmaf(a.w, w3.w, acc[i].w))));
        }
    }

    __syncthreads();   // in-place safety: all A reads complete before any store
#pragma unroll
    for (int i = 0; i < 8; ++i) {
        int m = row0 + i;
        if (m < M) {
            float4 v = acc[i];
            v.x = fmaxf(v.x, 0.f); v.y = fmaxf(v.y, 0.f);
            v.z = fmaxf(v.z, 0.f); v.w = fmaxf(v.w, 0.f);
            *(float4*)(C + (size_t)m * D_FEAT + col) = v;
        }
    }
}

extern "C" void kernel_launch(void* const* d_in, const int* in_sizes, int n_in,
                              void* d_out, int out_size, void* d_ws, size_t ws_size,
                              hipStream_t stream) {
    const float* x           = (const float*)d_in[0];
    const int*   edge_src    = (const int*)d_in[1];
    const int*   edge_dst    = (const int*)d_in[2];
    const float* w_comp      = (const float*)d_in[3];
    const float* bases       = (const float*)d_in[4];
    const float* loop_weight = (const float*)d_in[5];
    const float* h_bias      = (const float*)d_in[6];
    const float* ngnn_w      = (const float*)d_in[7];
    float* out = (float*)d_out;

    // workspace layout (base ~131.5 MB; +25.6 MB optional xb)
    char* ws = (char*)d_ws;
    size_t off = 0;
    __hip_bfloat162* y = (__hip_bfloat162*)(ws + off);
    int* ebuf2 = (int*)(ws + off);                 // 784*9216*4 = 28.9 MB, inside y
    off += (size_t)N_NODES * 512 * 2;              // 102.4 MB
    int* ebuf = (int*)(ws + off);
    off += (size_t)RE * 4;                         // 25.6 MB
    int* offsets = (int*)(ws + off);
    off += ((size_t)RN + 1) * 4;                   // 3.2 MB
    int* gcursor = (int*)(ws + off);
    off += 4096;
    unsigned short* wT = (unsigned short*)(ws + off);
    off += (size_t)128 * 640 * 2;                  // 160 KB
    uint* xb = (uint*)(ws + off);
    size_t xb_bytes = (size_t)N_NODES * 64 * 4;    // 25.6 MB
    const bool use_bf16_x = (ws_size >= off + xb_bytes);   // ws_size constant across calls

    const int GEMM_GRID = (N_NODES + 63) / 64;     // 1563

    // 0) one-time-per-call conversions (independent of partition)
    wcvt_kernel<<<(128 * 640 + 255) / 256, 256, 0, stream>>>(bases, loop_weight, wT);
    if (use_bf16_x)
        xcvt_kernel<<<(N_NODES * 64 + 255) / 256, 256, 0, stream>>>(x, xb);

    // 1) radix CSR build
    init_cursor_kernel<<<1, 1024, 0, stream>>>(gcursor);
    p1_kernel<<<P1_NWG, P1_TPB, 0, stream>>>(edge_src, edge_dst, gcursor, ebuf2);
    p2_kernel<<<NBKT, 1024, 0, stream>>>(gcursor, ebuf2, offsets, ebuf);

    // 2) fused gather -> y (bf16, basis-combined, deg-normalized)
    if (use_bf16_x)
        gather_kernel<true><<<(N_NODES + 3) / 4, 256, 0, stream>>>(
            x, xb, offsets, ebuf, w_comp, y);
    else
        gather_kernel<false><<<(N_NODES + 3) / 4, 256, 0, stream>>>(
            x, nullptr, offsets, ebuf, w_comp, y);

    // 3) out = relu([y|x] @ [bases;loop_w] + bias)  -- MFMA bf16
    gemm_big_mfma<<<GEMM_GRID, 256, 0, stream>>>(
        (const short*)y, x, wT, h_bias, out);

    // 4) NGNN in-place on d_out (fp32 vector)
    gemm128_kernel<<<GEMM_GRID, 256, 0, stream>>>(out, ngnn_w, out, N_NODES);
    gemm128_kernel<<<GEMM_GRID, 256, 0, stream>>>(out, ngnn_w + D_FEAT * D_FEAT, out, N_NODES);
}

// Round 7
// 820.812 us; speedup vs baseline: 21.3138x; 1.1224x over previous
//
#include <hip/hip_runtime.h>
#include <hip/hip_bf16.h>

#define N_NODES 100000
#define R_REL   8
#define E_EDGES 800000
#define D_FEAT  128
#define B_BASES 4
#define RN      (R_REL * N_NODES)          // 800000 keys (key = dst*8 + r)
#define RE      (R_REL * E_EDGES)          // 6.4M edges

// radix partition: 784 coarse buckets of 128 dst nodes each
#define NBKT    784
#define BKT_CAP 9216                       // mean 8163, +11 sigma slack
#define P1_TPB  256
#define P1_EPT  32
#define P1_CHUNK (P1_TPB * P1_EPT)         // 8192 edges / WG
#define P1_NWG  ((RE + P1_CHUNK - 1) / P1_CHUNK)   // 782

typedef __attribute__((ext_vector_type(8))) short short8;
typedef __attribute__((ext_vector_type(4))) float floatx4;

__global__ __launch_bounds__(1024) void init_cursor_kernel(int* __restrict__ gcursor) {
    int t = threadIdx.x;
    if (t < NBKT) gcursor[t] = t * BKT_CAP;
}

// x (fp32) -> xb (bf162 pairs)
__global__ __launch_bounds__(256) void xcvt_kernel(
    const float* __restrict__ x, uint* __restrict__ xb) {
    int i = blockIdx.x * 256 + threadIdx.x;          // over N*64 pairs
    if (i >= N_NODES * 64) return;
    float2 v = *(const float2*)(x + 2 * (size_t)i);
    __hip_bfloat162 h = __float22bfloat162_rn(v);
    xb[i] = *(uint*)&h;
}

// wT[n][k] = bf16( k<512 ? bases[k][n] : loop_weight[k-512][n] )
__global__ __launch_bounds__(256) void wcvt_kernel(
    const float* __restrict__ bases, const float* __restrict__ loopw,
    unsigned short* __restrict__ wT) {
    int idx = blockIdx.x * 256 + threadIdx.x;        // over 128*640
    if (idx >= 128 * 640) return;
    int n = idx / 640, k = idx % 640;
    float v = (k < 512) ? bases[(size_t)k * 128 + n] : loopw[(size_t)(k - 512) * 128 + n];
    __hip_bfloat16 h = __float2bfloat16(v);
    wT[idx] = *(unsigned short*)&h;
}

// wT2[l][n][k] = bf16(ngnn_w[l][k][n])   (2 layers, launched AFTER gather)
__global__ __launch_bounds__(256) void wcvt2_kernel(
    const float* __restrict__ ngnn_w, unsigned short* __restrict__ wT2) {
    int idx = blockIdx.x * 256 + threadIdx.x;        // over 2*128*128
    if (idx >= 2 * 128 * 128) return;
    int l = idx >> 14, rem = idx & 16383;
    int n = rem >> 7, k = rem & 127;
    float v = ngnn_w[(size_t)l * 16384 + (size_t)k * 128 + n];
    __hip_bfloat16 h = __float2bfloat16(v);
    wT2[idx] = *(unsigned short*)&h;
}

// ---- pass 1: partition edges into coarse dst-buckets (coalesced writes) ---
// record = src(17b) | dst_low(7b)<<17 | r(3b)<<24
__global__ __launch_bounds__(256) void p1_kernel(
    const int* __restrict__ src, const int* __restrict__ dst,
    int* __restrict__ gcursor, int* __restrict__ ebuf2) {
    __shared__ int hist[NBKT];
    __shared__ int cnt2[NBKT];
    __shared__ int basebkt[NBKT];
    __shared__ int lofs[NBKT];
    __shared__ int aux[256];
    __shared__ int recs[P1_CHUNK];           // 32 KB
    __shared__ unsigned short bb[P1_CHUNK];  // 16 KB
    int t = threadIdx.x;
    for (int i = t; i < NBKT; i += 256) { hist[i] = 0; cnt2[i] = 0; }
    __syncthreads();

    int e0 = blockIdx.x * P1_CHUNK;
    int rec[P1_EPT];
    int bkt[P1_EPT];
#pragma unroll
    for (int i = 0; i < P1_EPT; ++i) {
        int e = e0 + i * P1_TPB + t;         // coalesced
        if (e < RE) {
            int d = dst[e];
            int s = src[e];
            int r = e / E_EDGES;             // magic-mul division
            bkt[i] = d >> 7;
            rec[i] = s | ((d & 127) << 17) | (r << 24);
            atomicAdd(&hist[bkt[i]], 1);     // native int ds_add
        } else bkt[i] = -1;
    }
    __syncthreads();

    // exclusive scan of hist[784]: 4 consecutive per thread + Hillis-Steele on aux
    int k0 = t * 4;
    int c0 = (k0 + 0 < NBKT) ? hist[k0 + 0] : 0;
    int c1 = (k0 + 1 < NBKT) ? hist[k0 + 1] : 0;
    int c2 = (k0 + 2 < NBKT) ? hist[k0 + 2] : 0;
    int c3 = (k0 + 3 < NBKT) ? hist[k0 + 3] : 0;
    int s1 = c0 + c1, s2 = s1 + c2, s3 = s2 + c3;
    aux[t] = s3;
    __syncthreads();
    int vv = s3;
    for (int off = 1; off < 256; off <<= 1) {
        int yv = (t >= off) ? aux[t - off] : 0;
        __syncthreads();
        vv += yv;
        aux[t] = vv;
        __syncthreads();
    }
    int total = aux[255];
    int texcl = vv - s3;
    if (k0 + 0 < NBKT) lofs[k0 + 0] = texcl;
    if (k0 + 1 < NBKT) lofs[k0 + 1] = texcl + c0;
    if (k0 + 2 < NBKT) lofs[k0 + 2] = texcl + s1;
    if (k0 + 3 < NBKT) lofs[k0 + 3] = texcl + s2;
    __syncthreads();
    for (int i = t; i < NBKT; i += 256) {
        int hv = hist[i];
        basebkt[i] = (hv > 0) ? atomicAdd(&gcursor[i], hv) : 0;
    }
    __syncthreads();

    // reorder records into bucket-contiguous LDS slots
#pragma unroll
    for (int i = 0; i < P1_EPT; ++i) {
        if (bkt[i] >= 0) {
            int p = lofs[bkt[i]] + atomicAdd(&cnt2[bkt[i]], 1);
            recs[p] = rec[i];
            bb[p] = (unsigned short)bkt[i];
        }
    }
    __syncthreads();

    // writeout: consecutive i are mostly same-bucket runs
    for (int i = t; i < total; i += 256) {
        int b = bb[i];
        int p2 = basebkt[b] + (i - lofs[b]);
        if (p2 < (b + 1) * BKT_CAP) ebuf2[p2] = recs[i];
    }
}

// ---- pass 2: per-bucket CSR finalize; 1024 thr, thread t owns key t -------
__global__ __launch_bounds__(1024) void p2_kernel(
    const int* __restrict__ gcursor,
    const int* __restrict__ ebuf2,
    int* __restrict__ offsets,               // [RN+1]
    int* __restrict__ ebuf) {
    __shared__ int cursors[1024];
    __shared__ int aux[1024];
    const int t = threadIdx.x;
    const int bucket = blockIdx.x;

    // bucket base = exclusive prefix of per-bucket counts
    int c = 0;
    if (t < NBKT) {
        c = gcursor[t] - t * BKT_CAP;
        if (c > BKT_CAP) c = BKT_CAP;
    }
    aux[t] = c;
    __syncthreads();
    int vv = c;
    for (int off = 1; off < 1024; off <<= 1) {
        int yv = (t >= off) ? aux[t - off] : 0;
        __syncthreads();
        vv += yv;
        aux[t] = vv;
        __syncthreads();
    }
    int mybase = (bucket == 0) ? 0 : aux[bucket - 1];
    int mycnt  = aux[bucket] - mybase;
    __syncthreads();

    cursors[t] = 0;
    __syncthreads();

    // degree histogram
    const int* brec = ebuf2 + (size_t)bucket * BKT_CAP;
    for (int i = t; i < mycnt; i += 1024) {
        int rec = brec[i];
        int key = ((rec >> 17) & 127) * 8 + ((rec >> 24) & 7);
        atomicAdd(&cursors[key], 1);
    }
    __syncthreads();

    // exclusive scan of 1024 degrees
    int deg = cursors[t];
    aux[t] = deg;
    __syncthreads();
    int iv = deg;
    for (int off = 1; off < 1024; off <<= 1) {
        int yv = (t >= off) ? aux[t - off] : 0;
        __syncthreads();
        iv += yv;
        aux[t] = iv;
        __syncthreads();
    }
    int g0 = mybase + iv - deg;

    int idx = bucket * 1024 + t;             // == node*8 + r globally
    if (idx <= RN) offsets[idx] = g0;        // last active bucket writes sentinel RE
    __syncthreads();
    cursors[t] = g0;
    __syncthreads();

    // scatter src ids to exact CSR slots (stores land in a ~32 KB L2 window)
    for (int i = t; i < mycnt; i += 1024) {
        int rec = brec[i];
        int key = ((rec >> 17) & 127) * 8 + ((rec >> 24) & 7);
        int pos = atomicAdd(&cursors[key], 1);   // ds_add_rtn_u32
        ebuf[pos] = rec & 0x1FFFF;
    }
}

// ---- fused gather: all 8 relations -> 4 basis-combined bf16 outputs -------
template <bool XB>
__global__ __launch_bounds__(256) void gather_kernel(
    const float* __restrict__ x,
    const uint*  __restrict__ xb,          // [N][64] bf162 pairs
    const int*   __restrict__ offsets,
    const int*   __restrict__ ebuf,
    const float* __restrict__ w_comp,
    __hip_bfloat162* __restrict__ y) {     // [N][256] bf162
    int node = (blockIdx.x << 2) + (threadIdx.x >> 6);
    if (node >= N_NODES) return;
    int lane = threadIdx.x & 63;
    const float* xp = x + 2 * lane;
    const uint*  xbp = xb + lane;

    float2 acc[R_REL];
    float  inv[R_REL];
    int segbase = node * R_REL;
#pragma unroll
    for (int r = 0; r < R_REL; ++r) {
        int beg = offsets[segbase + r];
        int end = offsets[segbase + r + 1];
        int d = end - beg;
        inv[r] = 1.0f / (float)(d > 1 ? d : 1);
        float ax = 0.f, ay = 0.f;
        int i = beg;
        for (; i + 3 < end; i += 4) {
            int s0 = ebuf[i], s1 = ebuf[i + 1], s2 = ebuf[i + 2], s3 = ebuf[i + 3];
            if (XB) {
                uint u0 = xbp[(size_t)s0 * 64];
                uint u1 = xbp[(size_t)s1 * 64];
                uint u2 = xbp[(size_t)s2 * 64];
                uint u3 = xbp[(size_t)s3 * 64];
                ax += (__uint_as_float(u0 << 16) + __uint_as_float(u1 << 16))
                    + (__uint_as_float(u2 << 16) + __uint_as_float(u3 << 16));
                ay += (__uint_as_float(u0 & 0xFFFF0000u) + __uint_as_float(u1 & 0xFFFF0000u))
                    + (__uint_as_float(u2 & 0xFFFF0000u) + __uint_as_float(u3 & 0xFFFF0000u));
            } else {
                float2 a = *(const float2*)(xp + (size_t)s0 * D_FEAT);
                float2 b = *(const float2*)(xp + (size_t)s1 * D_FEAT);
                float2 cc = *(const float2*)(xp + (size_t)s2 * D_FEAT);
                float2 d2 = *(const float2*)(xp + (size_t)s3 * D_FEAT);
                ax += (a.x + b.x) + (cc.x + d2.x);
                ay += (a.y + b.y) + (cc.y + d2.y);
            }
        }
        for (; i < end; ++i) {
            int s = ebuf[i];
            if (XB) {
                uint u = xbp[(size_t)s * 64];
                ax += __uint_as_float(u << 16);
                ay += __uint_as_float(u & 0xFFFF0000u);
            } else {
                float2 a = *(const float2*)(xp + (size_t)s * D_FEAT);
                ax += a.x; ay += a.y;
            }
        }
        acc[r] = make_float2(ax, ay);
    }

#pragma unroll
    for (int b = 0; b < B_BASES; ++b) {
        float sx = 0.f, sy = 0.f;
#pragma unroll
        for (int r = 0; r < R_REL; ++r) {
            float coef = w_comp[r * B_BASES + b] * inv[r];
            sx = fmaf(coef, acc[r].x, sx);
            sy = fmaf(coef, acc[r].y, sy);
        }
        y[(size_t)node * 256 + b * 64 + lane] = __float22bfloat162_rn(make_float2(sx, sy));
    }
}

// ---- MFMA GEMM: hb1 = bf16(relu([y | bf16(x)] @ wT^T + bias)), K=640 ------
// frags: A[m=lane&15][k=quad*8+j], B[n=lane&15][k=quad*8+j],
// D[row=quad*4+reg][col=lane&15]  (verified layouts, m89/m120)
__global__ __launch_bounds__(256) void gemm_big_mfma(
    const short* __restrict__ y,           // [N][512] bf16
    const float* __restrict__ x,           // [N][128] fp32
    const unsigned short* __restrict__ wT, // [128][640] bf16
    const float* __restrict__ bias,
    unsigned short* __restrict__ hb1) {    // [N][128] bf16
    const int wave = threadIdx.x >> 6;
    const int lane = threadIdx.x & 63;
    const int quad = lane >> 4;
    const int l16  = lane & 15;
    const int row0 = blockIdx.x * 64 + wave * 16;
    int arow = row0 + l16;
    if (arow >= N_NODES) arow = N_NODES - 1;

    floatx4 acc[8];
#pragma unroll
    for (int nt = 0; nt < 8; ++nt) acc[nt] = (floatx4){0.f, 0.f, 0.f, 0.f};

    const short* yrow = y + (size_t)arow * 512;
    const float* xrow = x + (size_t)arow * 128;
    const int koff = quad * 8;

    // phase 1: K=512 from y
    for (int ks = 0; ks < 16; ++ks) {
        int k0 = ks * 32 + koff;
        short8 a = *(const short8*)(yrow + k0);
#pragma unroll
        for (int nt = 0; nt < 8; ++nt) {
            int n = nt * 16 + l16;
            short8 b = *(const short8*)((const short*)wT + (size_t)n * 640 + k0);
            acc[nt] = __builtin_amdgcn_mfma_f32_16x16x32_bf16(a, b, acc[nt], 0, 0, 0);
        }
    }
    // phase 2: K=128 from x, converted to bf16 in registers
#pragma unroll
    for (int ks = 0; ks < 4; ++ks) {
        int k0 = ks * 32 + koff;
        float4 fa = *(const float4*)(xrow + k0);
        float4 fb = *(const float4*)(xrow + k0 + 4);
        union { short8 s; uint u[4]; } ua;
        __hip_bfloat162 h0 = __float22bfloat162_rn(make_float2(fa.x, fa.y));
        __hip_bfloat162 h1 = __float22bfloat162_rn(make_float2(fa.z, fa.w));
        __hip_bfloat162 h2 = __float22bfloat162_rn(make_float2(fb.x, fb.y));
        __hip_bfloat162 h3 = __float22bfloat162_rn(make_float2(fb.z, fb.w));
        ua.u[0] = *(uint*)&h0; ua.u[1] = *(uint*)&h1;
        ua.u[2] = *(uint*)&h2; ua.u[3] = *(uint*)&h3;
#pragma unroll
        for (int nt = 0; nt < 8; ++nt) {
            int n = nt * 16 + l16;
            short8 b = *(const short8*)((const short*)wT + (size_t)n * 640 + 512 + k0);
            acc[nt] = __builtin_amdgcn_mfma_f32_16x16x32_bf16(ua.s, b, acc[nt], 0, 0, 0);
        }
    }

    // epilogue: bias + relu + bf16 store
#pragma unroll
    for (int nt = 0; nt < 8; ++nt) {
        int n = nt * 16 + l16;
        float bs = bias[n];
#pragma unroll
        for (int i = 0; i < 4; ++i) {
            int m = row0 + quad * 4 + i;
            if (m < N_NODES) {
                float v = fmaxf(acc[nt][i] + bs, 0.f);
                __hip_bfloat16 h = __float2bfloat16(v);
                hb1[(size_t)m * D_FEAT + n] = *(unsigned short*)&h;
            }
        }
    }
}

// ---- NGNN MFMA layer: C = relu(A @ wTl^T), A bf16 [N][128] ---------------
// OUT_BF16: store bf16, else fp32
template <bool OUT_BF16>
__global__ __launch_bounds__(256) void ngnn_mfma(
    const short* __restrict__ A,             // [N][128] bf16
    const unsigned short* __restrict__ wTl,  // [128][128] bf16, n-major
    void* __restrict__ C) {
    const int wave = threadIdx.x >> 6;
    const int lane = threadIdx.x & 63;
    const int quad = lane >> 4;
    const int l16  = lane & 15;
    const int row0 = blockIdx.x * 64 + wave * 16;
    int arow = row0 + l16;
    if (arow >= N_NODES) arow = N_NODES - 1;

    floatx4 acc[8];
#pragma unroll
    for (int nt = 0; nt < 8; ++nt) acc[nt] = (floatx4){0.f, 0.f, 0.f, 0.f};

    const short* ar = A + (size_t)arow * 128;
    const int koff = quad * 8;
#pragma unroll
    for (int ks = 0; ks < 4; ++ks) {
        int k0 = ks * 32 + koff;
        short8 a = *(const short8*)(ar + k0);
#pragma unroll
        for (int nt = 0; nt < 8; ++nt) {
            int n = nt * 16 + l16;
            short8 b = *(const short8*)((const short*)wTl + (size_t)n * 128 + k0);
            acc[nt] = __builtin_amdgcn_mfma_f32_16x16x32_bf16(a, b, acc[nt], 0, 0, 0);
        }
    }

#pragma unroll
    for (int nt = 0; nt < 8; ++nt) {
        int n = nt * 16 + l16;
#pragma unroll
        for (int i = 0; i < 4; ++i) {
            int m = row0 + quad * 4 + i;
            if (m < N_NODES) {
                float v = fmaxf(acc[nt][i], 0.f);
                if (OUT_BF16) {
                    __hip_bfloat16 h = __float2bfloat16(v);
                    ((unsigned short*)C)[(size_t)m * D_FEAT + n] = *(unsigned short*)&h;
                } else {
                    ((float*)C)[(size_t)m * D_FEAT + n] = v;
                }
            }
        }
    }
}

extern "C" void kernel_launch(void* const* d_in, const int* in_sizes, int n_in,
                              void* d_out, int out_size, void* d_ws, size_t ws_size,
                              hipStream_t stream) {
    const float* x           = (const float*)d_in[0];
    const int*   edge_src    = (const int*)d_in[1];
    const int*   edge_dst    = (const int*)d_in[2];
    const float* w_comp      = (const float*)d_in[3];
    const float* bases       = (const float*)d_in[4];
    const float* loop_weight = (const float*)d_in[5];
    const float* h_bias      = (const float*)d_in[6];
    const float* ngnn_w      = (const float*)d_in[7];
    float* out = (float*)d_out;

    // workspace layout (base ~131.5 MB; +25.6 MB optional xb)
    char* ws = (char*)d_ws;
    size_t off = 0;
    __hip_bfloat162* y = (__hip_bfloat162*)(ws + off);
    int* ebuf2 = (int*)(ws + off);                 // 784*9216*4 = 28.9 MB, inside y
    off += (size_t)N_NODES * 512 * 2;              // 102.4 MB
    int* ebuf = (int*)(ws + off);                  // 25.6 MB; reused as hb1 after gather
    unsigned short* hb1 = (unsigned short*)(ws + off);
    off += (size_t)RE * 4;
    int* offsets = (int*)(ws + off);               // 3.2 MB; tail reused for wT2 after gather
    unsigned short* wT2 = (unsigned short*)(ws + off);
    off += ((size_t)RN + 1) * 4;
    int* gcursor = (int*)(ws + off);
    off += 4096;
    unsigned short* wT = (unsigned short*)(ws + off);
    off += (size_t)128 * 640 * 2;                  // 160 KB
    uint* xb = (uint*)(ws + off);                  // 25.6 MB; reused as hb2 after gather
    unsigned short* hb2 = (unsigned short*)xb;
    size_t xb_bytes = (size_t)N_NODES * 64 * 4;
    const bool use_bf16_x = (ws_size >= off + xb_bytes);   // ws_size constant across calls

    const int GEMM_GRID = (N_NODES + 63) / 64;     // 1563

    // 0) conversions needed before/during partition
    wcvt_kernel<<<(128 * 640 + 255) / 256, 256, 0, stream>>>(bases, loop_weight, wT);
    if (use_bf16_x)
        xcvt_kernel<<<(N_NODES * 64 + 255) / 256, 256, 0, stream>>>(x, xb);

    // 1) radix CSR build
    init_cursor_kernel<<<1, 1024, 0, stream>>>(gcursor);
    p1_kernel<<<P1_NWG, P1_TPB, 0, stream>>>(edge_src, edge_dst, gcursor, ebuf2);
    p2_kernel<<<NBKT, 1024, 0, stream>>>(gcursor, ebuf2, offsets, ebuf);

    // 2) fused gather -> y (bf16, basis-combined, deg-normalized)
    if (use_bf16_x)
        gather_kernel<true><<<(N_NODES + 3) / 4, 256, 0, stream>>>(
            x, xb, offsets, ebuf, w_comp, y);
    else
        gather_kernel<false><<<(N_NODES + 3) / 4, 256, 0, stream>>>(
            x, nullptr, offsets, ebuf, w_comp, y);

    // offsets/ebuf/xb now dead: wT2 overlays offsets, hb1 overlays ebuf, hb2 overlays xb
    wcvt2_kernel<<<(2 * 128 * 128 + 255) / 256, 256, 0, stream>>>(ngnn_w, wT2);

    // 3) hb1 = bf16(relu([y|x] @ [bases;loop_w] + bias))  -- MFMA
    gemm_big_mfma<<<GEMM_GRID, 256, 0, stream>>>(
        (const short*)y, x, wT, h_bias, hb1);

    // 4) NGNN: hb2 = bf16(relu(hb1 @ w0));  out = relu(hb2 @ w1)  -- MFMA
    ngnn_mfma<true><<<GEMM_GRID, 256, 0, stream>>>(
        (const short*)hb1, wT2, (void*)hb2);
    ngnn_mfma<false><<<GEMM_GRID, 256, 0, stream>>>(
        (const short*)hb2, wT2 + 128 * 128, (void*)out);
}

// Round 8
// 704.305 us; speedup vs baseline: 24.8396x; 1.1654x over previous
//
#include <hip/hip_runtime.h>
#include <hip/hip_bf16.h>

#define N_NODES 100000
#define R_REL   8
#define E_EDGES 800000
#define D_FEAT  128
#define B_BASES 4
#define RN      (R_REL * N_NODES)
#define RE      (R_REL * E_EDGES)          // 6.4M edges

// radix partition: 784 coarse buckets of 128 dst nodes each
#define NBKT    784
#define BKT_CAP 9216                       // mean 8163, +11 sigma slack
#define P1_TPB  256
#define P1_EPT  32
#define P1_CHUNK (P1_TPB * P1_EPT)         // 8192 edges / WG
#define P1_NWG  ((RE + P1_CHUNK - 1) / P1_CHUNK)   // 782

typedef __attribute__((ext_vector_type(8))) short short8;
typedef __attribute__((ext_vector_type(4))) float floatx4;

__global__ __launch_bounds__(1024) void init_cursor_kernel(int* __restrict__ gcursor) {
    int t = threadIdx.x;
    if (t < NBKT) gcursor[t] = t * BKT_CAP;
}

// x (fp32) -> xb (bf162 pairs)
__global__ __launch_bounds__(256) void xcvt_kernel(
    const float* __restrict__ x, uint* __restrict__ xb) {
    int i = blockIdx.x * 256 + threadIdx.x;          // over N*64 pairs
    if (i >= N_NODES * 64) return;
    float2 v = *(const float2*)(x + 2 * (size_t)i);
    __hip_bfloat162 h = __float22bfloat162_rn(v);
    xb[i] = *(uint*)&h;
}

// wT[n][k] = bf16( k<512 ? bases[k][n] : loop_weight[k-512][n] )
__global__ __launch_bounds__(256) void wcvt_kernel(
    const float* __restrict__ bases, const float* __restrict__ loopw,
    unsigned short* __restrict__ wT) {
    int idx = blockIdx.x * 256 + threadIdx.x;        // over 128*640
    if (idx >= 128 * 640) return;
    int n = idx / 640, k = idx % 640;
    float v = (k < 512) ? bases[(size_t)k * 128 + n] : loopw[(size_t)(k - 512) * 128 + n];
    __hip_bfloat16 h = __float2bfloat16(v);
    wT[idx] = *(unsigned short*)&h;
}

// wT2[l][n][k] = bf16(ngnn_w[l][k][n])
__global__ __launch_bounds__(256) void wcvt2_kernel(
    const float* __restrict__ ngnn_w, unsigned short* __restrict__ wT2) {
    int idx = blockIdx.x * 256 + threadIdx.x;        // over 2*128*128
    if (idx >= 2 * 128 * 128) return;
    int l = idx >> 14, rem = idx & 16383;
    int n = rem >> 7, k = rem & 127;
    float v = ngnn_w[(size_t)l * 16384 + (size_t)k * 128 + n];
    __hip_bfloat16 h = __float2bfloat16(v);
    wT2[idx] = *(unsigned short*)&h;
}

// ---- pass 1: partition edges into coarse dst-buckets (coalesced writes) ---
// record = src(17b) | dst_low(7b)<<17 | r(3b)<<24
__global__ __launch_bounds__(256) void p1_kernel(
    const int* __restrict__ src, const int* __restrict__ dst,
    int* __restrict__ gcursor, int* __restrict__ ebuf2) {
    __shared__ int hist[NBKT];
    __shared__ int cnt2[NBKT];
    __shared__ int basebkt[NBKT];
    __shared__ int lofs[NBKT];
    __shared__ int aux[256];
    __shared__ int recs[P1_CHUNK];           // 32 KB
    __shared__ unsigned short bb[P1_CHUNK];  // 16 KB
    int t = threadIdx.x;
    for (int i = t; i < NBKT; i += 256) { hist[i] = 0; cnt2[i] = 0; }
    __syncthreads();

    int e0 = blockIdx.x * P1_CHUNK;
    int rec[P1_EPT];
    int bkt[P1_EPT];
#pragma unroll
    for (int i = 0; i < P1_EPT; ++i) {
        int e = e0 + i * P1_TPB + t;         // coalesced
        if (e < RE) {
            int d = dst[e];
            int s = src[e];
            int r = e / E_EDGES;             // magic-mul division
            bkt[i] = d >> 7;
            rec[i] = s | ((d & 127) << 17) | (r << 24);
            atomicAdd(&hist[bkt[i]], 1);     // native int ds_add
        } else bkt[i] = -1;
    }
    __syncthreads();

    // exclusive scan of hist[784]: 4 consecutive per thread + Hillis-Steele
    int k0 = t * 4;
    int c0 = (k0 + 0 < NBKT) ? hist[k0 + 0] : 0;
    int c1 = (k0 + 1 < NBKT) ? hist[k0 + 1] : 0;
    int c2 = (k0 + 2 < NBKT) ? hist[k0 + 2] : 0;
    int c3 = (k0 + 3 < NBKT) ? hist[k0 + 3] : 0;
    int s1 = c0 + c1, s2 = s1 + c2, s3 = s2 + c3;
    aux[t] = s3;
    __syncthreads();
    int vv = s3;
    for (int off = 1; off < 256; off <<= 1) {
        int yv = (t >= off) ? aux[t - off] : 0;
        __syncthreads();
        vv += yv;
        aux[t] = vv;
        __syncthreads();
    }
    int total = aux[255];
    int texcl = vv - s3;
    if (k0 + 0 < NBKT) lofs[k0 + 0] = texcl;
    if (k0 + 1 < NBKT) lofs[k0 + 1] = texcl + c0;
    if (k0 + 2 < NBKT) lofs[k0 + 2] = texcl + s1;
    if (k0 + 3 < NBKT) lofs[k0 + 3] = texcl + s2;
    __syncthreads();
    for (int i = t; i < NBKT; i += 256) {
        int hv = hist[i];
        basebkt[i] = (hv > 0) ? atomicAdd(&gcursor[i], hv) : 0;
    }
    __syncthreads();

    // reorder records into bucket-contiguous LDS slots
#pragma unroll
    for (int i = 0; i < P1_EPT; ++i) {
        if (bkt[i] >= 0) {
            int p = lofs[bkt[i]] + atomicAdd(&cnt2[bkt[i]], 1);
            recs[p] = rec[i];
            bb[p] = (unsigned short)bkt[i];
        }
    }
    __syncthreads();

    // writeout: consecutive i are mostly same-bucket runs
    for (int i = t; i < total; i += 256) {
        int b = bb[i];
        int p2 = basebkt[b] + (i - lofs[b]);
        if (p2 < (b + 1) * BKT_CAP) ebuf2[p2] = recs[i];
    }
}

// ---- fused sort+gather: per bucket, LDS sort -> per-node aggregate -> y ---
// 1024 thr (16 waves), 2 WGs/CU (80 KB LDS). Wave w owns nodes [w*8, w*8+8).
template <bool XB>
__global__ __launch_bounds__(1024, 8) void agg2_kernel(
    const float* __restrict__ x,
    const uint*  __restrict__ xb,          // [N][64] bf162 pairs
    const int*   __restrict__ gcursor,
    const int*   __restrict__ ebuf2,
    const float* __restrict__ w_comp,
    __hip_bfloat162* __restrict__ y) {     // [N][256] bf162
    __shared__ int raw[BKT_CAP];           // 36 KB
    __shared__ int sorted[BKT_CAP];        // 36 KB (first 1 KB doubles as scan aux)
    __shared__ int cursors[1024];          // 4 KB
    __shared__ int segbeg[1024];           // 4 KB
    const int t = threadIdx.x;
    const int bucket = blockIdx.x;

    int cnt = gcursor[bucket] - bucket * BKT_CAP;
    if (cnt > BKT_CAP) cnt = BKT_CAP;
    const int* brec = ebuf2 + (size_t)bucket * BKT_CAP;
    for (int i = t; i < cnt; i += 1024) raw[i] = brec[i];
    cursors[t] = 0;
    __syncthreads();

    // degree histogram over keys (dn*8 + r)
    for (int i = t; i < cnt; i += 1024) {
        int rec = raw[i];
        int key = ((rec >> 17) & 127) * 8 + ((rec >> 24) & 7);
        atomicAdd(&cursors[key], 1);
    }
    __syncthreads();

    // exclusive scan of 1024 degrees (aux aliases sorted[0..1023])
    int deg = cursors[t];
    int* aux = sorted;
    aux[t] = deg;
    __syncthreads();
    int vv = deg;
    for (int off = 1; off < 1024; off <<= 1) {
        int yv = (t >= off) ? aux[t - off] : 0;
        __syncthreads();
        vv += yv;
        aux[t] = vv;
        __syncthreads();
    }
    int beg = vv - deg;
    cursors[t] = beg;
    segbeg[t]  = beg;
    __syncthreads();

    // in-LDS scatter to sorted order (src ids only)
    for (int i = t; i < cnt; i += 1024) {
        int rec = raw[i];
        int key = ((rec >> 17) & 127) * 8 + ((rec >> 24) & 7);
        int pos = atomicAdd(&cursors[key], 1);   // ds_add_rtn_u32
        sorted[pos] = rec & 0x1FFFF;
    }
    __syncthreads();

    // gather: wave owns 8 nodes; per (node,r) segment sum then basis fold
    const int wid = t >> 6, lane = t & 63;
    const float* xp  = x + 2 * lane;
    const uint*  xbp = xb + lane;
    for (int nn = 0; nn < 8; ++nn) {
        int nl = wid * 8 + nn;
        int node = bucket * 128 + nl;
        int key0 = nl * 8;
        float2 acc[B_BASES];
#pragma unroll
        for (int b = 0; b < B_BASES; ++b) acc[b] = make_float2(0.f, 0.f);
#pragma unroll
        for (int r = 0; r < R_REL; ++r) {
            int b0 = segbeg[key0 + r];
            int e0 = cursors[key0 + r];      // post-scatter == segment end
            int d = e0 - b0;
            float inv = 1.0f / (float)(d > 1 ? d : 1);
            float ax = 0.f, ay = 0.f;
            int i = b0;
            for (; i + 3 < e0; i += 4) {
                int s0 = sorted[i], s1 = sorted[i + 1], s2 = sorted[i + 2], s3 = sorted[i + 3];
                if (XB) {
                    uint u0 = xbp[(size_t)s0 * 64];
                    uint u1 = xbp[(size_t)s1 * 64];
                    uint u2 = xbp[(size_t)s2 * 64];
                    uint u3 = xbp[(size_t)s3 * 64];
                    ax += (__uint_as_float(u0 << 16) + __uint_as_float(u1 << 16))
                        + (__uint_as_float(u2 << 16) + __uint_as_float(u3 << 16));
                    ay += (__uint_as_float(u0 & 0xFFFF0000u) + __uint_as_float(u1 & 0xFFFF0000u))
                        + (__uint_as_float(u2 & 0xFFFF0000u) + __uint_as_float(u3 & 0xFFFF0000u));
                } else {
                    float2 a = *(const float2*)(xp + (size_t)s0 * D_FEAT);
                    float2 b = *(const float2*)(xp + (size_t)s1 * D_FEAT);
                    float2 cc = *(const float2*)(xp + (size_t)s2 * D_FEAT);
                    float2 d2 = *(const float2*)(xp + (size_t)s3 * D_FEAT);
                    ax += (a.x + b.x) + (cc.x + d2.x);
                    ay += (a.y + b.y) + (cc.y + d2.y);
                }
            }
            for (; i < e0; ++i) {
                int s = sorted[i];
                if (XB) {
                    uint u = xbp[(size_t)s * 64];
                    ax += __uint_as_float(u << 16);
                    ay += __uint_as_float(u & 0xFFFF0000u);
                } else {
                    float2 a = *(const float2*)(xp + (size_t)s * D_FEAT);
                    ax += a.x; ay += a.y;
                }
            }
#pragma unroll
            for (int b = 0; b < B_BASES; ++b) {
                float coef = w_comp[r * B_BASES + b] * inv;
                acc[b].x = fmaf(coef, ax, acc[b].x);
                acc[b].y = fmaf(coef, ay, acc[b].y);
            }
        }
        if (node < N_NODES) {
#pragma unroll
            for (int b = 0; b < B_BASES; ++b)
                y[(size_t)node * 256 + b * 64 + lane] = __float22bfloat162_rn(acc[b]);
        }
    }
}

// ---- MFMA GEMM: hb1 = bf16(relu([y | bf16(x)] @ wT^T + bias)), K=640 ------
__global__ __launch_bounds__(256) void gemm_big_mfma(
    const short* __restrict__ y,           // [N][512] bf16
    const float* __restrict__ x,           // [N][128] fp32
    const unsigned short* __restrict__ wT, // [128][640] bf16
    const float* __restrict__ bias,
    unsigned short* __restrict__ hb1) {    // [N][128] bf16
    const int wave = threadIdx.x >> 6;
    const int lane = threadIdx.x & 63;
    const int quad = lane >> 4;
    const int l16  = lane & 15;
    const int row0 = blockIdx.x * 64 + wave * 16;
    int arow = row0 + l16;
    if (arow >= N_NODES) arow = N_NODES - 1;

    floatx4 acc[8];
#pragma unroll
    for (int nt = 0; nt < 8; ++nt) acc[nt] = (floatx4){0.f, 0.f, 0.f, 0.f};

    const short* yrow = y + (size_t)arow * 512;
    const float* xrow = x + (size_t)arow * 128;
    const int koff = quad * 8;

    for (int ks = 0; ks < 16; ++ks) {
        int k0 = ks * 32 + koff;
        short8 a = *(const short8*)(yrow + k0);
#pragma unroll
        for (int nt = 0; nt < 8; ++nt) {
            int n = nt * 16 + l16;
            short8 b = *(const short8*)((const short*)wT + (size_t)n * 640 + k0);
            acc[nt] = __builtin_amdgcn_mfma_f32_16x16x32_bf16(a, b, acc[nt], 0, 0, 0);
        }
    }
#pragma unroll
    for (int ks = 0; ks < 4; ++ks) {
        int k0 = ks * 32 + koff;
        float4 fa = *(const float4*)(xrow + k0);
        float4 fb = *(const float4*)(xrow + k0 + 4);
        union { short8 s; uint u[4]; } ua;
        __hip_bfloat162 h0 = __float22bfloat162_rn(make_float2(fa.x, fa.y));
        __hip_bfloat162 h1 = __float22bfloat162_rn(make_float2(fa.z, fa.w));
        __hip_bfloat162 h2 = __float22bfloat162_rn(make_float2(fb.x, fb.y));
        __hip_bfloat162 h3 = __float22bfloat162_rn(make_float2(fb.z, fb.w));
        ua.u[0] = *(uint*)&h0; ua.u[1] = *(uint*)&h1;
        ua.u[2] = *(uint*)&h2; ua.u[3] = *(uint*)&h3;
#pragma unroll
        for (int nt = 0; nt < 8; ++nt) {
            int n = nt * 16 + l16;
            short8 b = *(const short8*)((const short*)wT + (size_t)n * 640 + 512 + k0);
            acc[nt] = __builtin_amdgcn_mfma_f32_16x16x32_bf16(ua.s, b, acc[nt], 0, 0, 0);
        }
    }

#pragma unroll
    for (int nt = 0; nt < 8; ++nt) {
        int n = nt * 16 + l16;
        float bs = bias[n];
#pragma unroll
        for (int i = 0; i < 4; ++i) {
            int m = row0 + quad * 4 + i;
            if (m < N_NODES) {
                float v = fmaxf(acc[nt][i] + bs, 0.f);
                __hip_bfloat16 h = __float2bfloat16(v);
                hb1[(size_t)m * D_FEAT + n] = *(unsigned short*)&h;
            }
        }
    }
}

// ---- NGNN MFMA layer: C = relu(A @ wTl^T), A bf16 [N][128] ---------------
template <bool OUT_BF16>
__global__ __launch_bounds__(256) void ngnn_mfma(
    const short* __restrict__ A,             // [N][128] bf16
    const unsigned short* __restrict__ wTl,  // [128][128] bf16, n-major
    void* __restrict__ C) {
    const int wave = threadIdx.x >> 6;
    const int lane = threadIdx.x & 63;
    const int quad = lane >> 4;
    const int l16  = lane & 15;
    const int row0 = blockIdx.x * 64 + wave * 16;
    int arow = row0 + l16;
    if (arow >= N_NODES) arow = N_NODES - 1;

    floatx4 acc[8];
#pragma unroll
    for (int nt = 0; nt < 8; ++nt) acc[nt] = (floatx4){0.f, 0.f, 0.f, 0.f};

    const short* ar = A + (size_t)arow * 128;
    const int koff = quad * 8;
#pragma unroll
    for (int ks = 0; ks < 4; ++ks) {
        int k0 = ks * 32 + koff;
        short8 a = *(const short8*)(ar + k0);
#pragma unroll
        for (int nt = 0; nt < 8; ++nt) {
            int n = nt * 16 + l16;
            short8 b = *(const short8*)((const short*)wTl + (size_t)n * 128 + k0);
            acc[nt] = __builtin_amdgcn_mfma_f32_16x16x32_bf16(a, b, acc[nt], 0, 0, 0);
        }
    }

#pragma unroll
    for (int nt = 0; nt < 8; ++nt) {
        int n = nt * 16 + l16;
#pragma unroll
        for (int i = 0; i < 4; ++i) {
            int m = row0 + quad * 4 + i;
            if (m < N_NODES) {
                float v = fmaxf(acc[nt][i], 0.f);
                if (OUT_BF16) {
                    __hip_bfloat16 h = __float2bfloat16(v);
                    ((unsigned short*)C)[(size_t)m * D_FEAT + n] = *(unsigned short*)&h;
                } else {
                    ((float*)C)[(size_t)m * D_FEAT + n] = v;
                }
            }
        }
    }
}

extern "C" void kernel_launch(void* const* d_in, const int* in_sizes, int n_in,
                              void* d_out, int out_size, void* d_ws, size_t ws_size,
                              hipStream_t stream) {
    const float* x           = (const float*)d_in[0];
    const int*   edge_src    = (const int*)d_in[1];
    const int*   edge_dst    = (const int*)d_in[2];
    const float* w_comp      = (const float*)d_in[3];
    const float* bases       = (const float*)d_in[4];
    const float* loop_weight = (const float*)d_in[5];
    const float* h_bias      = (const float*)d_in[6];
    const float* ngnn_w      = (const float*)d_in[7];
    float* out = (float*)d_out;

    // workspace layout (~131.6 MB base; +25.6 MB optional xb)
    char* ws = (char*)d_ws;
    size_t off = 0;
    __hip_bfloat162* y = (__hip_bfloat162*)(ws + off);
    off += (size_t)N_NODES * 512 * 2;              // 102.4 MB
    int* ebuf2 = (int*)(ws + off);                 // 784*9216*4 = 28.9 MB
    unsigned short* hb1 = (unsigned short*)(ws + off);  // overlays ebuf2 (dead post-agg2)
    off += (size_t)NBKT * BKT_CAP * 4;
    int* gcursor = (int*)(ws + off);
    off += 4096;
    unsigned short* wT = (unsigned short*)(ws + off);
    off += (size_t)128 * 640 * 2;                  // 160 KB
    unsigned short* wT2 = (unsigned short*)(ws + off);
    off += (size_t)2 * 128 * 128 * 2;              // 64 KB
    uint* xb = (uint*)(ws + off);
    size_t xb_bytes = (size_t)N_NODES * 64 * 4;    // 25.6 MB
    const bool use_bf16_x = (ws_size >= off + xb_bytes);   // ws_size constant across calls
    // hb2: overlays xb (dead post-agg2) when present, else the y region (dead post-gemm_big)
    unsigned short* hb2 = use_bf16_x ? (unsigned short*)xb : (unsigned short*)y;

    const int GEMM_GRID = (N_NODES + 63) / 64;     // 1563

    // 0) weight/x conversions
    wcvt_kernel<<<(128 * 640 + 255) / 256, 256, 0, stream>>>(bases, loop_weight, wT);
    wcvt2_kernel<<<(2 * 128 * 128 + 255) / 256, 256, 0, stream>>>(ngnn_w, wT2);
    if (use_bf16_x)
        xcvt_kernel<<<(N_NODES * 64 + 255) / 256, 256, 0, stream>>>(x, xb);

    // 1) bucket partition
    init_cursor_kernel<<<1, 1024, 0, stream>>>(gcursor);
    p1_kernel<<<P1_NWG, P1_TPB, 0, stream>>>(edge_src, edge_dst, gcursor, ebuf2);

    // 2) fused LDS-sort + gather -> y (bf16, basis-combined, deg-normalized)
    if (use_bf16_x)
        agg2_kernel<true><<<NBKT, 1024, 0, stream>>>(x, xb, gcursor, ebuf2, w_comp, y);
    else
        agg2_kernel<false><<<NBKT, 1024, 0, stream>>>(x, nullptr, gcursor, ebuf2, w_comp, y);

    // 3) hb1 = bf16(relu([y|x] @ [bases;loop_w] + bias))  -- MFMA
    gemm_big_mfma<<<GEMM_GRID, 256, 0, stream>>>(
        (const short*)y, x, wT, h_bias, hb1);

    // 4) NGNN: hb2 = bf16(relu(hb1 @ w0));  out = relu(hb2 @ w1)  -- MFMA
    ngnn_mfma<true><<<GEMM_GRID, 256, 0, stream>>>(
        (const short*)hb1, wT2, (void*)hb2);
    ngnn_mfma<false><<<GEMM_GRID, 256, 0, stream>>>(
        (const short*)hb2, wT2 + 128 * 128, (void*)out);
}